// Round 1
// 214.970 us; speedup vs baseline: 1.5934x; 1.5934x over previous
//
#include <hip/hip_runtime.h>
#include <hip/hip_bf16.h>

// Problem: B=8, N=4096, E=65536, D=256
// h = x@W^T + b; agg = segment_sum(h[src]*m_s*m_t by tgt); h += agg/64;
// out = relu(LN(h)*gamma+beta) * mask
#define NN 4096
#define DIM 256
#define NE 65536
#define TOT_NODES 32768
#define TOT_EDGES 524288

// ---- runtime-dtype accessors (flags decided on device by detect_kernel) ----------
__device__ __forceinline__ float ldf(const void* p, int isbf, size_t i) {
    return isbf ? __bfloat162float(((const __hip_bfloat16*)p)[i]) : ((const float*)p)[i];
}
__device__ __forceinline__ void stf(void* p, int isbf, size_t i, float v) {
    if (isbf) ((__hip_bfloat16*)p)[i] = __float2bfloat16(v);
    else      ((float*)p)[i] = v;
}
__device__ __forceinline__ int ldi(const void* p, int is64, size_t i) {
    return is64 ? (int)((const long long*)p)[i] : ((const int*)p)[i];
}

// flags[0]=edge_index is int64, flags[1]=node_mask is int64, flags[2]=floats are bf16
__global__ void detect_kernel(const void* ei, const void* nm, const void* x, int* flags) {
    const int t = threadIdx.x;
    const long long ev = ((const long long*)ei)[t];
    const unsigned long long okE = __ballot(ev >= 0 && ev < NN);
    const long long mv = ((const long long*)nm)[t];
    const unsigned long long okM = __ballot(mv == 0 || mv == 1);
    // low 16 bits of each 32b word: for bf16 storage this is the even-index bf16
    // element (exp field biased near 127 for N(0,1)); for fp32 it's uniform mantissa bits.
    const unsigned int w = ((const unsigned int*)x)[t];
    const int e = (w >> 7) & 0xFF;
    const unsigned long long okF = __ballot(e >= 100 && e <= 140);
    if (t == 0) {
        flags[0] = (okE == ~0ULL) ? 1 : 0;
        flags[1] = (okM == ~0ULL) ? 1 : 0;
        flags[2] = (__popcll(okF) >= 40) ? 1 : 0;
    }
}

__global__ __launch_bounds__(256)
void init_kernel(int* __restrict__ counts) {
    counts[blockIdx.x * 256 + threadIdx.x] = 0;
}

// ---------------- MFMA GEMM: h[m][n] = sum_k x[m][k] * W[n][k] + b[n] --------------
// Block tile 128(M) x 64(N), BK=64, 256 threads = 4 waves, each wave owns 32x64.
// bf16 inputs: direct MFMA. fp32 inputs: hi/lo bf16 split, 3-term MFMA
// (hi*hi + hi*lo + lo*hi), error ~2^-16 relative.
// LDS tiles XOR-swizzled (byte ^= (row&7)<<4) to kill the 16-way bank conflict a
// linear [row][64] bf16 tile (128B stride) would have on ds_read_b128.

typedef __attribute__((ext_vector_type(8))) __bf16 bf16x8;
typedef __attribute__((ext_vector_type(4))) float  f32x4;

__device__ __forceinline__ unsigned short f2bf(float f) {
    unsigned u = __float_as_uint(f);
    u = (u + 0x7fffu + ((u >> 16) & 1u)) >> 16;
    return (unsigned short)u;
}
__device__ __forceinline__ float bf2f(unsigned short h) {
    return __uint_as_float(((unsigned)h) << 16);
}
// swizzled ushort index for element (row, col) in a [*][64]-bf16 LDS tile
__device__ __forceinline__ int swzi(int row, int col) {
    return (((row * 64 + col) * 2) ^ ((row & 7) << 4)) >> 1;
}
__device__ __forceinline__ bf16x8 frag_ld(const unsigned short* base, int row, int col) {
    const int byte = ((row * 64 + col) * 2) ^ ((row & 7) << 4);
    return *(const bf16x8*)((const char*)base + byte);
}

__global__ __launch_bounds__(256)
void gemm_kernel(const void* __restrict__ x, const void* __restrict__ w,
                 const void* __restrict__ bias, const int* __restrict__ flags,
                 float* __restrict__ h)
{
    __shared__ unsigned short Ahi[128 * 64];
    __shared__ unsigned short Alo[128 * 64];
    __shared__ unsigned short Bhi[64 * 64];
    __shared__ unsigned short Blo[64 * 64];

    const int fbf = flags[2];
    const int t = threadIdx.x;
    const int lane = t & 63;
    const int wv = t >> 6;
    const int m0 = (int)(blockIdx.x >> 2) * 128;
    const int n0 = (int)(blockIdx.x & 3) * 64;

    f32x4 acc[2][4];
#pragma unroll
    for (int mi = 0; mi < 2; ++mi)
#pragma unroll
        for (int nj = 0; nj < 4; ++nj)
            acc[mi][nj] = (f32x4){0.f, 0.f, 0.f, 0.f};

    for (int kt = 0; kt < 4; ++kt) {
        const int k0 = kt * 64;
        // ---- stage A tile 128x64 (8 x 16B-groups per thread) ----
#pragma unroll
        for (int i = 0; i < 8; ++i) {
            const int f   = i * 256 + t;
            const int row = f >> 4;           // 16 groups of 4 per row
            const int c4  = (f & 15) << 2;
            const int idx = swzi(row, c4);
            if (fbf) {
                const ushort4 u = *(const ushort4*)((const unsigned short*)x +
                                    (size_t)(m0 + row) * 256 + k0 + c4);
                *(ushort4*)&Ahi[idx] = u;     // raw bf16 bits, lo term unused
            } else {
                const float4 fv = *(const float4*)((const float*)x +
                                    (size_t)(m0 + row) * 256 + k0 + c4);
                const unsigned short h0 = f2bf(fv.x), h1 = f2bf(fv.y),
                                     h2 = f2bf(fv.z), h3 = f2bf(fv.w);
                *(ushort4*)&Ahi[idx] = make_ushort4(h0, h1, h2, h3);
                *(ushort4*)&Alo[idx] = make_ushort4(
                    f2bf(fv.x - bf2f(h0)), f2bf(fv.y - bf2f(h1)),
                    f2bf(fv.z - bf2f(h2)), f2bf(fv.w - bf2f(h3)));
            }
        }
        // ---- stage B tile 64x64 (4 x groups per thread) ----
#pragma unroll
        for (int i = 0; i < 4; ++i) {
            const int f   = i * 256 + t;
            const int row = f >> 4;
            const int c4  = (f & 15) << 2;
            const int idx = swzi(row, c4);
            if (fbf) {
                const ushort4 u = *(const ushort4*)((const unsigned short*)w +
                                    (size_t)(n0 + row) * 256 + k0 + c4);
                *(ushort4*)&Bhi[idx] = u;
            } else {
                const float4 fv = *(const float4*)((const float*)w +
                                    (size_t)(n0 + row) * 256 + k0 + c4);
                const unsigned short h0 = f2bf(fv.x), h1 = f2bf(fv.y),
                                     h2 = f2bf(fv.z), h3 = f2bf(fv.w);
                *(ushort4*)&Bhi[idx] = make_ushort4(h0, h1, h2, h3);
                *(ushort4*)&Blo[idx] = make_ushort4(
                    f2bf(fv.x - bf2f(h0)), f2bf(fv.y - bf2f(h1)),
                    f2bf(fv.z - bf2f(h2)), f2bf(fv.w - bf2f(h3)));
            }
        }
        __syncthreads();

        // ---- compute: 2 k-steps of 32 ----
#pragma unroll
        for (int kk = 0; kk < 64; kk += 32) {
            const int lr = lane & 15;
            const int lk = kk + ((lane >> 4) << 3);
            bf16x8 aH[2], bH[4];
            aH[0] = frag_ld(Ahi, wv * 32 + lr,      lk);
            aH[1] = frag_ld(Ahi, wv * 32 + 16 + lr, lk);
#pragma unroll
            for (int nj = 0; nj < 4; ++nj)
                bH[nj] = frag_ld(Bhi, nj * 16 + lr, lk);
#pragma unroll
            for (int mi = 0; mi < 2; ++mi)
#pragma unroll
                for (int nj = 0; nj < 4; ++nj)
                    acc[mi][nj] = __builtin_amdgcn_mfma_f32_16x16x32_bf16(
                        aH[mi], bH[nj], acc[mi][nj], 0, 0, 0);
            if (!fbf) {
                bf16x8 aL[2], bL[4];
                aL[0] = frag_ld(Alo, wv * 32 + lr,      lk);
                aL[1] = frag_ld(Alo, wv * 32 + 16 + lr, lk);
#pragma unroll
                for (int nj = 0; nj < 4; ++nj)
                    bL[nj] = frag_ld(Blo, nj * 16 + lr, lk);
#pragma unroll
                for (int mi = 0; mi < 2; ++mi)
#pragma unroll
                    for (int nj = 0; nj < 4; ++nj) {
                        acc[mi][nj] = __builtin_amdgcn_mfma_f32_16x16x32_bf16(
                            aH[mi], bL[nj], acc[mi][nj], 0, 0, 0);
                        acc[mi][nj] = __builtin_amdgcn_mfma_f32_16x16x32_bf16(
                            aL[mi], bH[nj], acc[mi][nj], 0, 0, 0);
                    }
            }
        }
        __syncthreads();
    }

    // ---- epilogue: +bias, write fp32 h. C/D map: col=lane&15, row=(lane>>4)*4+r ----
    const int lr = lane & 15;
    const int r4 = (lane >> 4) << 2;
#pragma unroll
    for (int nj = 0; nj < 4; ++nj) {
        const int n = n0 + nj * 16 + lr;
        const float bv = ldf(bias, fbf, n);
#pragma unroll
        for (int mi = 0; mi < 2; ++mi) {
            const int rb = m0 + wv * 32 + mi * 16 + r4;
#pragma unroll
            for (int r = 0; r < 4; ++r)
                h[(size_t)(rb + r) * 256 + n] = acc[mi][nj][r] + bv;
        }
    }
}

// ---------------- CSR build: count -> scan -> fill ---------------------------------
__global__ __launch_bounds__(256)
void count_kernel(const void* __restrict__ ei, const void* __restrict__ nm,
                  const int* __restrict__ flags, int* __restrict__ counts)
{
    const int e64 = flags[0], m64 = flags[1];
    const int tid = blockIdx.x * 256 + threadIdx.x;
    const int b = tid >> 16;          // NE = 65536
    const int e = tid & (NE - 1);
    const size_t eb = (size_t)b * 2 * NE;
    const int src = ldi(ei, e64, eb + e);
    const int tgt = ldi(ei, e64, eb + NE + e);
    const size_t mb = (size_t)b * NN;
    if (ldi(nm, m64, mb + src) && ldi(nm, m64, mb + tgt))
        atomicAdd(&counts[b * NN + tgt], 1);
}

// single block, 256 threads x 128; writes exclusive offsets and inits cursor
__global__ __launch_bounds__(256)
void scan_kernel(int* __restrict__ counts, int* __restrict__ offsets)
{
    __shared__ int sums[256];
    const int t = threadIdx.x;
    const int base = t * 128;
    int s = 0;
    for (int i = 0; i < 128; ++i) s += counts[base + i];
    sums[t] = s;
    __syncthreads();
    for (int off = 1; off < 256; off <<= 1) {
        int v = (t >= off) ? sums[t - off] : 0;
        __syncthreads();
        sums[t] += v;
        __syncthreads();
    }
    int run = sums[t] - s;
    for (int i = 0; i < 128; ++i) {
        const int c = counts[base + i];
        offsets[base + i] = run;
        counts[base + i] = run;     // cursor init for fill_kernel
        run += c;
    }
    if (t == 255) offsets[TOT_NODES] = sums[255];
}

__global__ __launch_bounds__(256)
void fill_kernel(const void* __restrict__ ei, const void* __restrict__ nm,
                 const int* __restrict__ flags,
                 int* __restrict__ cursor, int* __restrict__ bucket)
{
    const int e64 = flags[0], m64 = flags[1];
    const int tid = blockIdx.x * 256 + threadIdx.x;
    const int b = tid >> 16;
    const int e = tid & (NE - 1);
    const size_t eb = (size_t)b * 2 * NE;
    const int src = ldi(ei, e64, eb + e);
    const int tgt = ldi(ei, e64, eb + NE + e);
    const size_t mb = (size_t)b * NN;
    if (ldi(nm, m64, mb + src) && ldi(nm, m64, mb + tgt)) {
        int pos = atomicAdd(&cursor[b * NN + tgt], 1);
        bucket[pos] = src;
    }
}

// ---------------- gather + residual + LayerNorm + ReLU + mask ----------------------
__global__ __launch_bounds__(256)
void node_kernel(const float* __restrict__ h, const int* __restrict__ offsets,
                 const int* __restrict__ bucket, const void* __restrict__ nm,
                 const int* __restrict__ flags,
                 const void* __restrict__ gamma, const void* __restrict__ beta,
                 void* __restrict__ out)
{
    const int bt = blockIdx.x;
    const int d = threadIdx.x;
    const size_t obase = (size_t)bt * DIM;
    const int m64 = flags[1], fbf = flags[2];
    if (!ldi(nm, m64, bt)) { stf(out, fbf, obase + d, 0.f); return; }
    const int b = bt >> 12;     // NN = 4096
    const float* hb = h + ((size_t)b << 12) * DIM;
    const float self = h[obase + d];
    const int s0 = offsets[bt], s1 = offsets[bt + 1];
    float a0 = 0.f, a1 = 0.f, a2 = 0.f, a3 = 0.f;
    int j = s0;
    for (; j + 4 <= s1; j += 4) {
        const int i0 = bucket[j], i1 = bucket[j + 1], i2 = bucket[j + 2], i3 = bucket[j + 3];
        a0 += hb[(size_t)i0 * DIM + d];
        a1 += hb[(size_t)i1 * DIM + d];
        a2 += hb[(size_t)i2 * DIM + d];
        a3 += hb[(size_t)i3 * DIM + d];
    }
    for (; j < s1; ++j) a0 += hb[(size_t)bucket[j] * DIM + d];
    const float acc = self + ((a0 + a1) + (a2 + a3)) * 0.015625f;   // /sqrt(4096)

    float v1 = acc, v2 = acc * acc;
#pragma unroll
    for (int off = 32; off > 0; off >>= 1) {
        v1 += __shfl_down(v1, off, 64);
        v2 += __shfl_down(v2, off, 64);
    }
    __shared__ float red[8];
    const int wv = d >> 6, ln = d & 63;
    if (ln == 0) { red[wv] = v1; red[4 + wv] = v2; }
    __syncthreads();
    const float S1 = red[0] + red[1] + red[2] + red[3];
    const float S2 = red[4] + red[5] + red[6] + red[7];
    const float mu = S1 * (1.f / 256.f);
    const float var = S2 * (1.f / 256.f) - mu * mu;
    const float inv = rsqrtf(var + 1e-5f);
    float y = (acc - mu) * inv * ldf(gamma, fbf, d) + ldf(beta, fbf, d);
    y = fmaxf(y, 0.f);
    stf(out, fbf, obase + d, y);
}

// host-side sentinel buffer for launch-failure diagnosis (static lifetime: safe
// for async H2D copy; value encodes the first failing stage as absmax ~ 1e4*stage)
static float g_sentinel[256];

extern "C" void kernel_launch(void* const* d_in, const int* in_sizes, int n_in,
                              void* d_out, int out_size, void* d_ws, size_t ws_size,
                              hipStream_t stream)
{
    (void)in_sizes; (void)n_in; (void)out_size;
    const void* x     = d_in[0];
    const void* W     = d_in[1];
    const void* bias  = d_in[2];
    const void* gamma = d_in[3];
    const void* beta  = d_in[4];
    const void* ei    = d_in[5];
    const void* nm    = d_in[6];

    char* ws = (char*)d_ws;
    int* flags   = (int*)ws;                 // @0        12 B
    int* counts  = (int*)(ws + 256);         // @256      131072 B (becomes cursor)
    int* offsets = (int*)(ws + 131328);      // @131328   131076 B
    int* bucket  = (int*)(ws + 262656);      // @262656   2097152 B
    float* h     = (float*)(ws + 2359808);   // @2359808  33554432 B (fp32 h)

    int fail = 0;
    hipGetLastError();  // clear any pre-existing error
#define CHK(stage) do { if (!fail && hipGetLastError() != hipSuccess) fail = (stage); } while (0)

    detect_kernel<<<1, 64, 0, stream>>>(ei, nm, x, flags);                       CHK(1);
    init_kernel<<<TOT_NODES / 256, 256, 0, stream>>>(counts);                    CHK(2);
    gemm_kernel<<<(TOT_NODES / 128) * (DIM / 64), 256, 0, stream>>>(x, W, bias, flags, h); CHK(3);
    count_kernel<<<TOT_EDGES / 256, 256, 0, stream>>>(ei, nm, flags, counts);    CHK(4);
    scan_kernel<<<1, 256, 0, stream>>>(counts, offsets);                         CHK(5);
    fill_kernel<<<TOT_EDGES / 256, 256, 0, stream>>>(ei, nm, flags, counts, bucket); CHK(6);
    node_kernel<<<TOT_NODES, 256, 0, stream>>>(h, offsets, bucket, nm, flags,
                                               gamma, beta, d_out);              CHK(7);
#undef CHK

    if (fail) {   // deterministic per-environment -> graph-capture safe
        for (int i = 0; i < 256; ++i) g_sentinel[i] = 10000.f * (float)fail;
        hipMemcpyAsync(d_out, g_sentinel, sizeof(g_sentinel),
                       hipMemcpyHostToDevice, stream);
    }
}

// Round 2
// 172.205 us; speedup vs baseline: 1.9891x; 1.2483x over previous
//
#include <hip/hip_runtime.h>
#include <hip/hip_bf16.h>

// Problem: B=8, N=4096, E=65536, D=256
// h = x@W^T + b; agg = segment_sum(h[src]*m_s*m_t by tgt); h += agg/64;
// out = relu(LN(h)*gamma+beta) * mask
#define NN 4096
#define DIM 256
#define NE 65536
#define TOT_NODES 32768
#define TOT_EDGES 524288

// ---- runtime-dtype accessors (flags decided on device by detect_kernel) ----------
__device__ __forceinline__ float ldf(const void* p, int isbf, size_t i) {
    return isbf ? __bfloat162float(((const __hip_bfloat16*)p)[i]) : ((const float*)p)[i];
}
__device__ __forceinline__ void stf(void* p, int isbf, size_t i, float v) {
    if (isbf) ((__hip_bfloat16*)p)[i] = __float2bfloat16(v);
    else      ((float*)p)[i] = v;
}
__device__ __forceinline__ int ldi(const void* p, int is64, size_t i) {
    return is64 ? (int)((const long long*)p)[i] : ((const int*)p)[i];
}

// flags[0]=edge_index is int64, flags[1]=node_mask is int64, flags[2]=floats are bf16
__global__ void detect_kernel(const void* ei, const void* nm, const void* x, int* flags) {
    const int t = threadIdx.x;
    const long long ev = ((const long long*)ei)[t];
    const unsigned long long okE = __ballot(ev >= 0 && ev < NN);
    const long long mv = ((const long long*)nm)[t];
    const unsigned long long okM = __ballot(mv == 0 || mv == 1);
    const unsigned int w = ((const unsigned int*)x)[t];
    const int e = (w >> 7) & 0xFF;
    const unsigned long long okF = __ballot(e >= 100 && e <= 140);
    if (t == 0) {
        flags[0] = (okE == ~0ULL) ? 1 : 0;
        flags[1] = (okM == ~0ULL) ? 1 : 0;
        flags[2] = (__popcll(okF) >= 40) ? 1 : 0;
    }
}

__global__ __launch_bounds__(256)
void init_kernel(int* __restrict__ counts) {
    counts[blockIdx.x * 256 + threadIdx.x] = 0;
}

// ---------------- MFMA GEMM: h[m][n] = sum_k x[m][k] * W[n][k] + b[n] --------------
// Block tile 128(M) x 256(N = full D), BK=64, 512 threads = 8 waves (2m x 4n grid),
// each wave owns a 64x64 sub-tile (4x4 16x16 frags). Grid = 256 blocks -> x fetched
// from HBM exactly once (round-1 counter showed 4x refetch = 66 MB at 128x64 tiles).
// bf16 path: global_load_lds width-16 staging with PRE-SWIZZLED global source
// (linear LDS dest as HW requires; XOR swizzle (row&7)<<4 is an involution, so the
// source group index is cg = (slot&7)^(row&7)). fp32 path: register staging with
// hi/lo bf16 split, 3-term MFMA.

typedef __attribute__((ext_vector_type(8))) __bf16 bf16x8;
typedef __attribute__((ext_vector_type(4))) float  f32x4;

__device__ __forceinline__ unsigned short f2bf(float f) {
    unsigned u = __float_as_uint(f);
    u = (u + 0x7fffu + ((u >> 16) & 1u)) >> 16;
    return (unsigned short)u;
}
__device__ __forceinline__ float bf2f(unsigned short h) {
    return __uint_as_float(((unsigned)h) << 16);
}
__device__ __forceinline__ void cvt_hilo(float4 f, ushort4* hi, ushort4* lo) {
    const unsigned short h0 = f2bf(f.x), h1 = f2bf(f.y), h2 = f2bf(f.z), h3 = f2bf(f.w);
    *hi = make_ushort4(h0, h1, h2, h3);
    *lo = make_ushort4(f2bf(f.x - bf2f(h0)), f2bf(f.y - bf2f(h1)),
                       f2bf(f.z - bf2f(h2)), f2bf(f.w - bf2f(h3)));
}
// swizzled ds_read_b128 of 8 bf16 at (row, col) in a [*][64]-bf16 LDS tile
__device__ __forceinline__ bf16x8 frag_ld(const unsigned short* base, int row, int col) {
    const int byte = ((row * 64 + col) * 2) ^ ((row & 7) << 4);
    return *(const bf16x8*)((const char*)base + byte);
}
__device__ __forceinline__ void gload16(const void* g, void* l) {
    __builtin_amdgcn_global_load_lds(
        (const __attribute__((address_space(1))) unsigned int*)g,
        (__attribute__((address_space(3))) unsigned int*)l, 16, 0, 0);
}

__global__ __launch_bounds__(512)
void gemm_kernel(const void* __restrict__ x, const void* __restrict__ w,
                 const void* __restrict__ bias, const int* __restrict__ flags,
                 float* __restrict__ h)
{
    __shared__ unsigned short Ahi[128 * 64];   // 16 KB
    __shared__ unsigned short Bhi[256 * 64];   // 32 KB
    __shared__ unsigned short Alo[128 * 64];   // fp32-fallback lo terms
    __shared__ unsigned short Blo[256 * 64];   // total 96 KB -> 1 block/CU (grid=256)

    const int fbf = flags[2];
    const int t = threadIdx.x;
    const int lane = t & 63;
    const int wid = t >> 6;
    const int wr = wid >> 2;        // 0..1 : m-half (64 rows)
    const int wc = wid & 3;         // 0..3 : n-quarter (64 cols)
    const int m0 = (int)blockIdx.x * 128;

    f32x4 acc[4][4];
#pragma unroll
    for (int mi = 0; mi < 4; ++mi)
#pragma unroll
        for (int nj = 0; nj < 4; ++nj)
            acc[mi][nj] = (f32x4){0.f, 0.f, 0.f, 0.f};

    for (int kt = 0; kt < 4; ++kt) {
        const int k0 = kt * 64;
        if (fbf) {
            const unsigned short* xp = (const unsigned short*)x;
            const unsigned short* wp = (const unsigned short*)w;
            // A tile: 128 rows x 8 groups = 1024 slots, 2 per thread
#pragma unroll
            for (int i = 0; i < 2; ++i) {
                const int s = i * 512 + t;
                const int row = s >> 3, cg = (s & 7) ^ (row & 7);
                gload16(xp + (size_t)(m0 + row) * 256 + k0 + cg * 8, &Ahi[s * 8]);
            }
            // B tile: 256 rows x 8 groups = 2048 slots, 4 per thread
#pragma unroll
            for (int i = 0; i < 4; ++i) {
                const int s = i * 512 + t;
                const int row = s >> 3, cg = (s & 7) ^ (row & 7);
                gload16(wp + (size_t)row * 256 + k0 + cg * 8, &Bhi[s * 8]);
            }
        } else {
            const float* xp = (const float*)x;
            const float* wp = (const float*)w;
#pragma unroll
            for (int i = 0; i < 2; ++i) {
                const int s = i * 512 + t;
                const int row = s >> 3, cg = (s & 7) ^ (row & 7);
                const float* src = xp + (size_t)(m0 + row) * 256 + k0 + cg * 8;
                const float4 f0 = *(const float4*)src, f1 = *(const float4*)(src + 4);
                ushort4 h0, l0, h1, l1;
                cvt_hilo(f0, &h0, &l0); cvt_hilo(f1, &h1, &l1);
                *(ushort4*)&Ahi[s * 8]     = h0; *(ushort4*)&Ahi[s * 8 + 4] = h1;
                *(ushort4*)&Alo[s * 8]     = l0; *(ushort4*)&Alo[s * 8 + 4] = l1;
            }
#pragma unroll
            for (int i = 0; i < 4; ++i) {
                const int s = i * 512 + t;
                const int row = s >> 3, cg = (s & 7) ^ (row & 7);
                const float* src = wp + (size_t)row * 256 + k0 + cg * 8;
                const float4 f0 = *(const float4*)src, f1 = *(const float4*)(src + 4);
                ushort4 h0, l0, h1, l1;
                cvt_hilo(f0, &h0, &l0); cvt_hilo(f1, &h1, &l1);
                *(ushort4*)&Bhi[s * 8]     = h0; *(ushort4*)&Bhi[s * 8 + 4] = h1;
                *(ushort4*)&Blo[s * 8]     = l0; *(ushort4*)&Blo[s * 8 + 4] = l1;
            }
        }
        __syncthreads();   // drains vmcnt(0) -> staged tiles visible

#pragma unroll
        for (int kk = 0; kk < 64; kk += 32) {
            const int lr = lane & 15;
            const int lk = kk + ((lane >> 4) << 3);
            bf16x8 aH[4], bH[4];
#pragma unroll
            for (int mi = 0; mi < 4; ++mi)
                aH[mi] = frag_ld(Ahi, wr * 64 + mi * 16 + lr, lk);
#pragma unroll
            for (int nj = 0; nj < 4; ++nj)
                bH[nj] = frag_ld(Bhi, wc * 64 + nj * 16 + lr, lk);
#pragma unroll
            for (int mi = 0; mi < 4; ++mi)
#pragma unroll
                for (int nj = 0; nj < 4; ++nj)
                    acc[mi][nj] = __builtin_amdgcn_mfma_f32_16x16x32_bf16(
                        aH[mi], bH[nj], acc[mi][nj], 0, 0, 0);
            if (!fbf) {
                bf16x8 aL[4], bL[4];
#pragma unroll
                for (int mi = 0; mi < 4; ++mi)
                    aL[mi] = frag_ld(Alo, wr * 64 + mi * 16 + lr, lk);
#pragma unroll
                for (int nj = 0; nj < 4; ++nj)
                    bL[nj] = frag_ld(Blo, wc * 64 + nj * 16 + lr, lk);
#pragma unroll
                for (int mi = 0; mi < 4; ++mi)
#pragma unroll
                    for (int nj = 0; nj < 4; ++nj) {
                        acc[mi][nj] = __builtin_amdgcn_mfma_f32_16x16x32_bf16(
                            aH[mi], bL[nj], acc[mi][nj], 0, 0, 0);
                        acc[mi][nj] = __builtin_amdgcn_mfma_f32_16x16x32_bf16(
                            aL[mi], bH[nj], acc[mi][nj], 0, 0, 0);
                    }
            }
        }
        __syncthreads();   // all reads done before next kt's staging overwrites
    }

    // ---- epilogue: +bias, fp32 h. C/D map: col=lane&15, row=(lane>>4)*4+r ----
    const int lr = lane & 15;
    const int r4 = (lane >> 4) << 2;
#pragma unroll
    for (int nj = 0; nj < 4; ++nj) {
        const int n = wc * 64 + nj * 16 + lr;
        const float bv = ldf(bias, fbf, n);
#pragma unroll
        for (int mi = 0; mi < 4; ++mi) {
            const int rb = m0 + wr * 64 + mi * 16 + r4;
#pragma unroll
            for (int r = 0; r < 4; ++r)
                h[(size_t)(rb + r) * 256 + n] = acc[mi][nj][r] + bv;
        }
    }
}

// ---------------- CSR build: count -> scan -> fill ---------------------------------
__global__ __launch_bounds__(256)
void count_kernel(const void* __restrict__ ei, const void* __restrict__ nm,
                  const int* __restrict__ flags, int* __restrict__ counts)
{
    const int e64 = flags[0], m64 = flags[1];
    const int tid = blockIdx.x * 256 + threadIdx.x;
    const int b = tid >> 16;          // NE = 65536
    const int e = tid & (NE - 1);
    const size_t eb = (size_t)b * 2 * NE;
    const int src = ldi(ei, e64, eb + e);
    const int tgt = ldi(ei, e64, eb + NE + e);
    const size_t mb = (size_t)b * NN;
    if (ldi(nm, m64, mb + src) && ldi(nm, m64, mb + tgt))
        atomicAdd(&counts[b * NN + tgt], 1);
}

// single block, 256 threads x 128; writes exclusive offsets and inits cursor
__global__ __launch_bounds__(256)
void scan_kernel(int* __restrict__ counts, int* __restrict__ offsets)
{
    __shared__ int sums[256];
    const int t = threadIdx.x;
    const int base = t * 128;
    int s = 0;
    for (int i = 0; i < 128; ++i) s += counts[base + i];
    sums[t] = s;
    __syncthreads();
    for (int off = 1; off < 256; off <<= 1) {
        int v = (t >= off) ? sums[t - off] : 0;
        __syncthreads();
        sums[t] += v;
        __syncthreads();
    }
    int run = sums[t] - s;
    for (int i = 0; i < 128; ++i) {
        const int c = counts[base + i];
        offsets[base + i] = run;
        counts[base + i] = run;     // cursor init for fill_kernel
        run += c;
    }
    if (t == 255) offsets[TOT_NODES] = sums[255];
}

__global__ __launch_bounds__(256)
void fill_kernel(const void* __restrict__ ei, const void* __restrict__ nm,
                 const int* __restrict__ flags,
                 int* __restrict__ cursor, int* __restrict__ bucket)
{
    const int e64 = flags[0], m64 = flags[1];
    const int tid = blockIdx.x * 256 + threadIdx.x;
    const int b = tid >> 16;
    const int e = tid & (NE - 1);
    const size_t eb = (size_t)b * 2 * NE;
    const int src = ldi(ei, e64, eb + e);
    const int tgt = ldi(ei, e64, eb + NE + e);
    const size_t mb = (size_t)b * NN;
    if (ldi(nm, m64, mb + src) && ldi(nm, m64, mb + tgt)) {
        int pos = atomicAdd(&cursor[b * NN + tgt], 1);
        bucket[pos] = src;
    }
}

// ---------------- gather + residual + LayerNorm + ReLU + mask ----------------------
// One wave per node, float4 per lane (64 x 4 = 256 dims). Gathered neighbor rows are
// 1 KB per wave-instruction; LN reduce is pure shfl_xor (no LDS, no barrier).
__global__ __launch_bounds__(64)
void node_kernel(const float* __restrict__ h, const int* __restrict__ offsets,
                 const int* __restrict__ bucket, const void* __restrict__ nm,
                 const int* __restrict__ flags,
                 const void* __restrict__ gamma, const void* __restrict__ beta,
                 void* __restrict__ out)
{
    const int bt = blockIdx.x;
    const int lane = threadIdx.x;          // 0..63
    const int m64 = flags[1], fbf = flags[2];
    const size_t o4 = (size_t)bt * 64 + lane;     // float4/ushort4 index
    if (!ldi(nm, m64, bt)) {
        if (fbf) ((ushort4*)out)[o4] = make_ushort4(0, 0, 0, 0);
        else     ((float4*)out)[o4]  = make_float4(0.f, 0.f, 0.f, 0.f);
        return;
    }
    const int b = bt >> 12;     // NN = 4096
    const float4* hb = (const float4*)h + ((size_t)b << 12) * 64;
    const float4 self = ((const float4*)h)[o4];
    const int s0 = offsets[bt], s1 = offsets[bt + 1];
    float4 a0 = make_float4(0.f, 0.f, 0.f, 0.f), a1 = a0, a2 = a0, a3 = a0;
    int j = s0;
    for (; j + 4 <= s1; j += 4) {
        const float4 v0 = hb[(size_t)bucket[j]     * 64 + lane];
        const float4 v1 = hb[(size_t)bucket[j + 1] * 64 + lane];
        const float4 v2 = hb[(size_t)bucket[j + 2] * 64 + lane];
        const float4 v3 = hb[(size_t)bucket[j + 3] * 64 + lane];
        a0.x += v0.x; a0.y += v0.y; a0.z += v0.z; a0.w += v0.w;
        a1.x += v1.x; a1.y += v1.y; a1.z += v1.z; a1.w += v1.w;
        a2.x += v2.x; a2.y += v2.y; a2.z += v2.z; a2.w += v2.w;
        a3.x += v3.x; a3.y += v3.y; a3.z += v3.z; a3.w += v3.w;
    }
    for (; j < s1; ++j) {
        const float4 v = hb[(size_t)bucket[j] * 64 + lane];
        a0.x += v.x; a0.y += v.y; a0.z += v.z; a0.w += v.w;
    }
    float4 acc;
    acc.x = self.x + ((a0.x + a1.x) + (a2.x + a3.x)) * 0.015625f;  // /sqrt(4096)
    acc.y = self.y + ((a0.y + a1.y) + (a2.y + a3.y)) * 0.015625f;
    acc.z = self.z + ((a0.z + a1.z) + (a2.z + a3.z)) * 0.015625f;
    acc.w = self.w + ((a0.w + a1.w) + (a2.w + a3.w)) * 0.015625f;

    float v1r = (acc.x + acc.y) + (acc.z + acc.w);
    float v2r = (acc.x * acc.x + acc.y * acc.y) + (acc.z * acc.z + acc.w * acc.w);
#pragma unroll
    for (int off = 32; off > 0; off >>= 1) {
        v1r += __shfl_xor(v1r, off, 64);
        v2r += __shfl_xor(v2r, off, 64);
    }
    const float mu  = v1r * (1.f / 256.f);
    const float var = v2r * (1.f / 256.f) - mu * mu;
    const float inv = rsqrtf(var + 1e-5f);
    const int d0 = lane * 4;
    float y0 = (acc.x - mu) * inv * ldf(gamma, fbf, d0)     + ldf(beta, fbf, d0);
    float y1 = (acc.y - mu) * inv * ldf(gamma, fbf, d0 + 1) + ldf(beta, fbf, d0 + 1);
    float y2 = (acc.z - mu) * inv * ldf(gamma, fbf, d0 + 2) + ldf(beta, fbf, d0 + 2);
    float y3 = (acc.w - mu) * inv * ldf(gamma, fbf, d0 + 3) + ldf(beta, fbf, d0 + 3);
    y0 = fmaxf(y0, 0.f); y1 = fmaxf(y1, 0.f); y2 = fmaxf(y2, 0.f); y3 = fmaxf(y3, 0.f);
    if (fbf) ((ushort4*)out)[o4] = make_ushort4(f2bf(y0), f2bf(y1), f2bf(y2), f2bf(y3));
    else     ((float4*)out)[o4]  = make_float4(y0, y1, y2, y3);
}

// host-side sentinel buffer for launch-failure diagnosis (static lifetime: safe
// for async H2D copy; value encodes the first failing stage as absmax ~ 1e4*stage)
static float g_sentinel[256];

extern "C" void kernel_launch(void* const* d_in, const int* in_sizes, int n_in,
                              void* d_out, int out_size, void* d_ws, size_t ws_size,
                              hipStream_t stream)
{
    (void)in_sizes; (void)n_in; (void)out_size;
    const void* x     = d_in[0];
    const void* W     = d_in[1];
    const void* bias  = d_in[2];
    const void* gamma = d_in[3];
    const void* beta  = d_in[4];
    const void* ei    = d_in[5];
    const void* nm    = d_in[6];

    char* ws = (char*)d_ws;
    int* flags   = (int*)ws;                 // @0        12 B
    int* counts  = (int*)(ws + 256);         // @256      131072 B (becomes cursor)
    int* offsets = (int*)(ws + 131328);      // @131328   131076 B
    int* bucket  = (int*)(ws + 262656);      // @262656   2097152 B
    float* h     = (float*)(ws + 2359808);   // @2359808  33554432 B (fp32 h)

    int fail = 0;
    hipGetLastError();  // clear any pre-existing error
#define CHK(stage) do { if (!fail && hipGetLastError() != hipSuccess) fail = (stage); } while (0)

    detect_kernel<<<1, 64, 0, stream>>>(ei, nm, x, flags);                       CHK(1);
    init_kernel<<<TOT_NODES / 256, 256, 0, stream>>>(counts);                    CHK(2);
    gemm_kernel<<<TOT_NODES / 128, 512, 0, stream>>>(x, W, bias, flags, h);      CHK(3);
    count_kernel<<<TOT_EDGES / 256, 256, 0, stream>>>(ei, nm, flags, counts);    CHK(4);
    scan_kernel<<<1, 256, 0, stream>>>(counts, offsets);                         CHK(5);
    fill_kernel<<<TOT_EDGES / 256, 256, 0, stream>>>(ei, nm, flags, counts, bucket); CHK(6);
    node_kernel<<<TOT_NODES, 64, 0, stream>>>(h, offsets, bucket, nm, flags,
                                              gamma, beta, d_out);               CHK(7);
#undef CHK

    if (fail) {   // deterministic per-environment -> graph-capture safe
        for (int i = 0; i < 256; ++i) g_sentinel[i] = 10000.f * (float)fail;
        hipMemcpyAsync(d_out, g_sentinel, sizeof(g_sentinel),
                       hipMemcpyHostToDevice, stream);
    }
}

// Round 3
// 164.456 us; speedup vs baseline: 2.0829x; 1.0471x over previous
//
#include <hip/hip_runtime.h>
#include <hip/hip_bf16.h>

// Problem: B=8, N=4096, E=65536, D=256
// h = x@W^T + b; agg = segment_sum(h[src]*m_s*m_t by tgt); h += agg/64;
// out = relu(LN(h)*gamma+beta) * mask
#define NN 4096
#define DIM 256
#define NE 65536
#define TOT_NODES 32768
#define TOT_EDGES 524288

// ---- runtime-dtype accessors (flags decided on device by detect logic) -----------
__device__ __forceinline__ float ldf(const void* p, int isbf, size_t i) {
    return isbf ? __bfloat162float(((const __hip_bfloat16*)p)[i]) : ((const float*)p)[i];
}
__device__ __forceinline__ int ldi(const void* p, int is64, size_t i) {
    return is64 ? (int)((const long long*)p)[i] : ((const int*)p)[i];
}

// flags[0]=edge_index is int64, flags[1]=node_mask is int64, flags[2]=floats are bf16
// Fused: grid=128 zeroes counts; block 0 / wave 0 additionally runs dtype detection.
__global__ __launch_bounds__(256)
void init_detect_kernel(const void* ei, const void* nm, const void* x,
                        int* __restrict__ flags, int* __restrict__ counts)
{
    const int t = threadIdx.x;
    counts[blockIdx.x * 256 + t] = 0;
    if (blockIdx.x == 0 && t < 64) {
        const long long ev = ((const long long*)ei)[t];
        const unsigned long long okE = __ballot(ev >= 0 && ev < NN);
        const long long mv = ((const long long*)nm)[t];
        const unsigned long long okM = __ballot(mv == 0 || mv == 1);
        const unsigned int w = ((const unsigned int*)x)[t];
        const int e = (w >> 7) & 0xFF;
        const unsigned long long okF = __ballot(e >= 100 && e <= 140);
        if (t == 0) {
            flags[0] = (okE == ~0ULL) ? 1 : 0;
            flags[1] = (okM == ~0ULL) ? 1 : 0;
            flags[2] = (__popcll(okF) >= 40) ? 1 : 0;
        }
    }
}

// ---------------- MFMA GEMM: h[m][n] = sum_k x[m][k] * W[n][k] + b[n] --------------
// Block tile 128(M) x 256(N = full D), BK=64, 512 threads = 8 waves (2m x 4n),
// wave sub-tile 64x64 (4x4 16x16x32 frags). Grid = 256 (1 block/CU, 96 KB LDS);
// x fetched from HBM exactly once. bf16 path: DOUBLE-BUFFERED global_load_lds
// width-16 staging with pre-swizzled global source (linear LDS dest; XOR swizzle
// (row&7)<<4 is an involution so source group cg=(slot&7)^(row&7)); prefetch of
// k-tile kt+1 is issued before compute of kt -> 1 barrier per k-tile, load latency
// hidden under MFMA. fp32 path: register staging hi/lo bf16 split (buffers 0=hi,1=lo).

typedef __attribute__((ext_vector_type(8))) __bf16 bf16x8;
typedef __attribute__((ext_vector_type(4))) float  f32x4;

__device__ __forceinline__ unsigned short f2bf(float f) {
    unsigned u = __float_as_uint(f);
    u = (u + 0x7fffu + ((u >> 16) & 1u)) >> 16;
    return (unsigned short)u;
}
__device__ __forceinline__ float bf2f(unsigned short h) {
    return __uint_as_float(((unsigned)h) << 16);
}
__device__ __forceinline__ void cvt_hilo(float4 f, ushort4* hi, ushort4* lo) {
    const unsigned short h0 = f2bf(f.x), h1 = f2bf(f.y), h2 = f2bf(f.z), h3 = f2bf(f.w);
    *hi = make_ushort4(h0, h1, h2, h3);
    *lo = make_ushort4(f2bf(f.x - bf2f(h0)), f2bf(f.y - bf2f(h1)),
                       f2bf(f.z - bf2f(h2)), f2bf(f.w - bf2f(h3)));
}
// swizzled ds_read_b128 of 8 bf16 at (row, col) in a [*][64]-bf16 LDS tile
__device__ __forceinline__ bf16x8 frag_ld(const unsigned short* base, int row, int col) {
    const int byte = ((row * 64 + col) * 2) ^ ((row & 7) << 4);
    return *(const bf16x8*)((const char*)base + byte);
}
__device__ __forceinline__ void gload16(const void* g, void* l) {
    __builtin_amdgcn_global_load_lds(
        (const __attribute__((address_space(1))) unsigned int*)g,
        (__attribute__((address_space(3))) unsigned int*)l, 16, 0, 0);
}

__global__ __launch_bounds__(512)
void gemm_kernel(const void* __restrict__ x, const void* __restrict__ w,
                 const void* __restrict__ bias, const int* __restrict__ flags,
                 float* __restrict__ h)
{
    __shared__ unsigned short As[2][128 * 64];   // 2 x 16 KB
    __shared__ unsigned short Bs[2][256 * 64];   // 2 x 32 KB  -> 96 KB total

    const int fbf = flags[2];
    const int t = threadIdx.x;
    const int lane = t & 63;
    const int wid = t >> 6;
    const int wr = wid >> 2;        // m-half (64 rows)
    const int wc = wid & 3;         // n-quarter (64 cols)
    const int m0 = (int)blockIdx.x * 128;

    f32x4 acc[4][4];
#pragma unroll
    for (int mi = 0; mi < 4; ++mi)
#pragma unroll
        for (int nj = 0; nj < 4; ++nj)
            acc[mi][nj] = (f32x4){0.f, 0.f, 0.f, 0.f};

    const int lr = lane & 15;
    const int lk8 = (lane >> 4) << 3;

    auto compute_hh = [&](const unsigned short* Ab, const unsigned short* Bb) {
#pragma unroll
        for (int kk = 0; kk < 64; kk += 32) {
            const int lk = kk + lk8;
            bf16x8 aH[4], bH[4];
#pragma unroll
            for (int mi = 0; mi < 4; ++mi)
                aH[mi] = frag_ld(Ab, wr * 64 + mi * 16 + lr, lk);
#pragma unroll
            for (int nj = 0; nj < 4; ++nj)
                bH[nj] = frag_ld(Bb, wc * 64 + nj * 16 + lr, lk);
#pragma unroll
            for (int mi = 0; mi < 4; ++mi)
#pragma unroll
                for (int nj = 0; nj < 4; ++nj)
                    acc[mi][nj] = __builtin_amdgcn_mfma_f32_16x16x32_bf16(
                        aH[mi], bH[nj], acc[mi][nj], 0, 0, 0);
        }
    };

    if (fbf) {
        const unsigned short* xp = (const unsigned short*)x;
        const unsigned short* wp = (const unsigned short*)w;
        auto stage = [&](int kt, int buf) {
            const int k0 = kt * 64;
#pragma unroll
            for (int i = 0; i < 2; ++i) {           // A: 1024 slots, 2/thread
                const int s = i * 512 + t;
                const int row = s >> 3, cg = (s & 7) ^ (row & 7);
                gload16(xp + (size_t)(m0 + row) * 256 + k0 + cg * 8, &As[buf][s * 8]);
            }
#pragma unroll
            for (int i = 0; i < 4; ++i) {           // B: 2048 slots, 4/thread
                const int s = i * 512 + t;
                const int row = s >> 3, cg = (s & 7) ^ (row & 7);
                gload16(wp + (size_t)row * 256 + k0 + cg * 8, &Bs[buf][s * 8]);
            }
        };
        stage(0, 0);
        for (int kt = 0; kt < 4; ++kt) {
            __syncthreads();                    // drains vmcnt -> buf[kt&1] ready;
            if (kt < 3) stage(kt + 1, (kt + 1) & 1);   // also fences buf overwrite
            compute_hh(As[kt & 1], Bs[kt & 1]);
        }
    } else {
        // fp32 fallback: buffers [0]=hi, [1]=lo, single-buffered, 3-term MFMA
        const float* xp = (const float*)x;
        const float* wp = (const float*)w;
        for (int kt = 0; kt < 4; ++kt) {
            const int k0 = kt * 64;
#pragma unroll
            for (int i = 0; i < 2; ++i) {
                const int s = i * 512 + t;
                const int row = s >> 3, cg = (s & 7) ^ (row & 7);
                const float* src = xp + (size_t)(m0 + row) * 256 + k0 + cg * 8;
                const float4 f0 = *(const float4*)src, f1 = *(const float4*)(src + 4);
                ushort4 h0, l0, h1, l1;
                cvt_hilo(f0, &h0, &l0); cvt_hilo(f1, &h1, &l1);
                *(ushort4*)&As[0][s * 8]     = h0; *(ushort4*)&As[0][s * 8 + 4] = h1;
                *(ushort4*)&As[1][s * 8]     = l0; *(ushort4*)&As[1][s * 8 + 4] = l1;
            }
#pragma unroll
            for (int i = 0; i < 4; ++i) {
                const int s = i * 512 + t;
                const int row = s >> 3, cg = (s & 7) ^ (row & 7);
                const float* src = wp + (size_t)row * 256 + k0 + cg * 8;
                const float4 f0 = *(const float4*)src, f1 = *(const float4*)(src + 4);
                ushort4 h0, l0, h1, l1;
                cvt_hilo(f0, &h0, &l0); cvt_hilo(f1, &h1, &l1);
                *(ushort4*)&Bs[0][s * 8]     = h0; *(ushort4*)&Bs[0][s * 8 + 4] = h1;
                *(ushort4*)&Bs[1][s * 8]     = l0; *(ushort4*)&Bs[1][s * 8 + 4] = l1;
            }
            __syncthreads();
            compute_hh(As[0], Bs[0]);
#pragma unroll
            for (int kk = 0; kk < 64; kk += 32) {
                const int lk = kk + lk8;
                bf16x8 aH[4], bH[4], aL[4], bL[4];
#pragma unroll
                for (int mi = 0; mi < 4; ++mi) {
                    aH[mi] = frag_ld(As[0], wr * 64 + mi * 16 + lr, lk);
                    aL[mi] = frag_ld(As[1], wr * 64 + mi * 16 + lr, lk);
                }
#pragma unroll
                for (int nj = 0; nj < 4; ++nj) {
                    bH[nj] = frag_ld(Bs[0], wc * 64 + nj * 16 + lr, lk);
                    bL[nj] = frag_ld(Bs[1], wc * 64 + nj * 16 + lr, lk);
                }
#pragma unroll
                for (int mi = 0; mi < 4; ++mi)
#pragma unroll
                    for (int nj = 0; nj < 4; ++nj) {
                        acc[mi][nj] = __builtin_amdgcn_mfma_f32_16x16x32_bf16(
                            aH[mi], bL[nj], acc[mi][nj], 0, 0, 0);
                        acc[mi][nj] = __builtin_amdgcn_mfma_f32_16x16x32_bf16(
                            aL[mi], bH[nj], acc[mi][nj], 0, 0, 0);
                    }
            }
            __syncthreads();
        }
    }

    // ---- epilogue: +bias, fp32 h. C/D map: col=lane&15, row=(lane>>4)*4+r ----
    const int r4 = (lane >> 4) << 2;
#pragma unroll
    for (int nj = 0; nj < 4; ++nj) {
        const int n = wc * 64 + nj * 16 + lr;
        const float bv = ldf(bias, fbf, n);
#pragma unroll
        for (int mi = 0; mi < 4; ++mi) {
            const int rb = m0 + wr * 64 + mi * 16 + r4;
#pragma unroll
            for (int r = 0; r < 4; ++r)
                h[(size_t)(rb + r) * 256 + n] = acc[mi][nj][r] + bv;
        }
    }
}

// ---------------- CSR build: count -> scan -> fill ---------------------------------
// 2 edges per thread, vector loads of the index pairs.
__global__ __launch_bounds__(256)
void count_kernel(const void* __restrict__ ei, const void* __restrict__ nm,
                  const int* __restrict__ flags, int* __restrict__ counts)
{
    const int e64 = flags[0], m64 = flags[1];
    const int tid = blockIdx.x * 256 + threadIdx.x;   // 0..262143
    const int b = tid >> 15;                          // 32768 threads/batch
    const int k = (tid & 32767) << 1;
    const size_t eb = (size_t)b * 2 * NE;
    int s0, s1, t0, t1;
    if (e64) {
        const longlong2 sv = *(const longlong2*)((const long long*)ei + eb + k);
        const longlong2 tv = *(const longlong2*)((const long long*)ei + eb + NE + k);
        s0 = (int)sv.x; s1 = (int)sv.y; t0 = (int)tv.x; t1 = (int)tv.y;
    } else {
        const int2 sv = *(const int2*)((const int*)ei + eb + k);
        const int2 tv = *(const int2*)((const int*)ei + eb + NE + k);
        s0 = sv.x; s1 = sv.y; t0 = tv.x; t1 = tv.y;
    }
    const size_t mb = (size_t)b * NN;
    if (ldi(nm, m64, mb + s0) && ldi(nm, m64, mb + t0))
        atomicAdd(&counts[b * NN + t0], 1);
    if (ldi(nm, m64, mb + s1) && ldi(nm, m64, mb + t1))
        atomicAdd(&counts[b * NN + t1], 1);
}

// Coalesced transposed scan: thread t owns nodes {i*256+t}. The node->range mapping
// is an arbitrary bijection (bucket order is irrelevant); offsets[] = start, and
// after fill_kernel the cursor array holds start+count = end pointer per node.
__global__ __launch_bounds__(256)
void scan_kernel(int* __restrict__ counts, int* __restrict__ offsets)
{
    __shared__ int sums[256];
    const int t = threadIdx.x;
    int s = 0;
    for (int i = 0; i < 128; ++i) s += counts[i * 256 + t];   // coalesced
    sums[t] = s;
    __syncthreads();
    for (int off = 1; off < 256; off <<= 1) {
        int v = (t >= off) ? sums[t - off] : 0;
        __syncthreads();
        sums[t] += v;
        __syncthreads();
    }
    int run = sums[t] - s;
    for (int i = 0; i < 128; ++i) {                           // coalesced
        const int idx = i * 256 + t;
        const int c = counts[idx];
        offsets[idx] = run;
        counts[idx] = run;      // cursor init for fill_kernel
        run += c;
    }
}

__global__ __launch_bounds__(256)
void fill_kernel(const void* __restrict__ ei, const void* __restrict__ nm,
                 const int* __restrict__ flags,
                 int* __restrict__ cursor, int* __restrict__ bucket)
{
    const int e64 = flags[0], m64 = flags[1];
    const int tid = blockIdx.x * 256 + threadIdx.x;
    const int b = tid >> 15;
    const int k = (tid & 32767) << 1;
    const size_t eb = (size_t)b * 2 * NE;
    int s0, s1, t0, t1;
    if (e64) {
        const longlong2 sv = *(const longlong2*)((const long long*)ei + eb + k);
        const longlong2 tv = *(const longlong2*)((const long long*)ei + eb + NE + k);
        s0 = (int)sv.x; s1 = (int)sv.y; t0 = (int)tv.x; t1 = (int)tv.y;
    } else {
        const int2 sv = *(const int2*)((const int*)ei + eb + k);
        const int2 tv = *(const int2*)((const int*)ei + eb + NE + k);
        s0 = sv.x; s1 = sv.y; t0 = tv.x; t1 = tv.y;
    }
    const size_t mb = (size_t)b * NN;
    if (ldi(nm, m64, mb + s0) && ldi(nm, m64, mb + t0))
        bucket[atomicAdd(&cursor[b * NN + t0], 1)] = s0;
    if (ldi(nm, m64, mb + s1) && ldi(nm, m64, mb + t1))
        bucket[atomicAdd(&cursor[b * NN + t1], 1)] = s1;
}

// ---------------- gather + residual + LayerNorm + ReLU + mask ----------------------
// 4 waves per 256-thread block, one node per wave (no barriers, full occupancy).
// float4 per lane (64 x 4 = 256 dims); LN reduce is pure shfl_xor.
__global__ __launch_bounds__(256)
void node_kernel(const float* __restrict__ h, const int* __restrict__ offsets,
                 const int* __restrict__ ends, const int* __restrict__ bucket,
                 const void* __restrict__ nm, const int* __restrict__ flags,
                 const void* __restrict__ gamma, const void* __restrict__ beta,
                 void* __restrict__ out)
{
    const int bt = blockIdx.x * 4 + (threadIdx.x >> 6);
    const int lane = threadIdx.x & 63;
    const int m64 = flags[1], fbf = flags[2];
    const size_t o4 = (size_t)bt * 64 + lane;     // float4/ushort4 index
    if (!ldi(nm, m64, bt)) {
        if (fbf) ((ushort4*)out)[o4] = make_ushort4(0, 0, 0, 0);
        else     ((float4*)out)[o4]  = make_float4(0.f, 0.f, 0.f, 0.f);
        return;
    }
    const int b = bt >> 12;     // NN = 4096
    const float4* hb = (const float4*)h + ((size_t)b << 12) * 64;
    const float4 self = ((const float4*)h)[o4];
    const int s0 = offsets[bt], s1 = ends[bt];
    float4 a0 = make_float4(0.f, 0.f, 0.f, 0.f), a1 = a0, a2 = a0, a3 = a0;
    int j = s0;
    for (; j + 4 <= s1; j += 4) {
        const float4 v0 = hb[(size_t)bucket[j]     * 64 + lane];
        const float4 v1 = hb[(size_t)bucket[j + 1] * 64 + lane];
        const float4 v2 = hb[(size_t)bucket[j + 2] * 64 + lane];
        const float4 v3 = hb[(size_t)bucket[j + 3] * 64 + lane];
        a0.x += v0.x; a0.y += v0.y; a0.z += v0.z; a0.w += v0.w;
        a1.x += v1.x; a1.y += v1.y; a1.z += v1.z; a1.w += v1.w;
        a2.x += v2.x; a2.y += v2.y; a2.z += v2.z; a2.w += v2.w;
        a3.x += v3.x; a3.y += v3.y; a3.z += v3.z; a3.w += v3.w;
    }
    for (; j < s1; ++j) {
        const float4 v = hb[(size_t)bucket[j] * 64 + lane];
        a0.x += v.x; a0.y += v.y; a0.z += v.z; a0.w += v.w;
    }
    float4 acc;
    acc.x = self.x + ((a0.x + a1.x) + (a2.x + a3.x)) * 0.015625f;  // /sqrt(4096)
    acc.y = self.y + ((a0.y + a1.y) + (a2.y + a3.y)) * 0.015625f;
    acc.z = self.z + ((a0.z + a1.z) + (a2.z + a3.z)) * 0.015625f;
    acc.w = self.w + ((a0.w + a1.w) + (a2.w + a3.w)) * 0.015625f;

    float v1r = (acc.x + acc.y) + (acc.z + acc.w);
    float v2r = (acc.x * acc.x + acc.y * acc.y) + (acc.z * acc.z + acc.w * acc.w);
#pragma unroll
    for (int off = 32; off > 0; off >>= 1) {
        v1r += __shfl_xor(v1r, off, 64);
        v2r += __shfl_xor(v2r, off, 64);
    }
    const float mu  = v1r * (1.f / 256.f);
    const float var = v2r * (1.f / 256.f) - mu * mu;
    const float inv = rsqrtf(var + 1e-5f);
    const int d0 = lane * 4;
    float y0 = (acc.x - mu) * inv * ldf(gamma, fbf, d0)     + ldf(beta, fbf, d0);
    float y1 = (acc.y - mu) * inv * ldf(gamma, fbf, d0 + 1) + ldf(beta, fbf, d0 + 1);
    float y2 = (acc.z - mu) * inv * ldf(gamma, fbf, d0 + 2) + ldf(beta, fbf, d0 + 2);
    float y3 = (acc.w - mu) * inv * ldf(gamma, fbf, d0 + 3) + ldf(beta, fbf, d0 + 3);
    y0 = fmaxf(y0, 0.f); y1 = fmaxf(y1, 0.f); y2 = fmaxf(y2, 0.f); y3 = fmaxf(y3, 0.f);
    if (fbf) ((ushort4*)out)[o4] = make_ushort4(f2bf(y0), f2bf(y1), f2bf(y2), f2bf(y3));
    else     ((float4*)out)[o4]  = make_float4(y0, y1, y2, y3);
}

// host-side sentinel buffer for launch-failure diagnosis (static lifetime: safe
// for async H2D copy; value encodes the first failing stage as absmax ~ 1e4*stage)
static float g_sentinel[256];

extern "C" void kernel_launch(void* const* d_in, const int* in_sizes, int n_in,
                              void* d_out, int out_size, void* d_ws, size_t ws_size,
                              hipStream_t stream)
{
    (void)in_sizes; (void)n_in; (void)out_size;
    const void* x     = d_in[0];
    const void* W     = d_in[1];
    const void* bias  = d_in[2];
    const void* gamma = d_in[3];
    const void* beta  = d_in[4];
    const void* ei    = d_in[5];
    const void* nm    = d_in[6];

    char* ws = (char*)d_ws;
    int* flags   = (int*)ws;                 // @0        12 B
    int* counts  = (int*)(ws + 256);         // @256      131072 B (becomes cursor/end)
    int* offsets = (int*)(ws + 131328);      // @131328   131072 B
    int* bucket  = (int*)(ws + 262656);      // @262656   2097152 B
    float* h     = (float*)(ws + 2359808);   // @2359808  33554432 B (fp32 h)

    int fail = 0;
    hipGetLastError();  // clear any pre-existing error
#define CHK(stage) do { if (!fail && hipGetLastError() != hipSuccess) fail = (stage); } while (0)

    init_detect_kernel<<<TOT_NODES / 256, 256, 0, stream>>>(ei, nm, x, flags, counts); CHK(1);
    gemm_kernel<<<TOT_NODES / 128, 512, 0, stream>>>(x, W, bias, flags, h);            CHK(2);
    count_kernel<<<TOT_EDGES / 512, 256, 0, stream>>>(ei, nm, flags, counts);          CHK(3);
    scan_kernel<<<1, 256, 0, stream>>>(counts, offsets);                               CHK(4);
    fill_kernel<<<TOT_EDGES / 512, 256, 0, stream>>>(ei, nm, flags, counts, bucket);   CHK(5);
    node_kernel<<<TOT_NODES / 4, 256, 0, stream>>>(h, offsets, counts, bucket, nm,
                                                   flags, gamma, beta, d_out);         CHK(6);
#undef CHK

    if (fail) {   // deterministic per-environment -> graph-capture safe
        for (int i = 0; i < 256; ++i) g_sentinel[i] = 10000.f * (float)fail;
        hipMemcpyAsync(d_out, g_sentinel, sizeof(g_sentinel),
                       hipMemcpyHostToDevice, stream);
    }
}

// Round 4
// 157.951 us; speedup vs baseline: 2.1686x; 1.0412x over previous
//
#include <hip/hip_runtime.h>
#include <hip/hip_bf16.h>

// Problem: B=8, N=4096, E=65536, D=256
// h = x@W^T + b; agg = segment_sum(h[src]*m_s*m_t by tgt); h += agg/64;
// out = relu(LN(h)*gamma+beta) * mask
#define NN 4096
#define DIM 256
#define NE 65536
#define TOT_NODES 32768
#define TOT_EDGES 524288

// ---- runtime-dtype accessors (flags decided on device by detect logic) -----------
__device__ __forceinline__ float ldf(const void* p, int isbf, size_t i) {
    return isbf ? __bfloat162float(((const __hip_bfloat16*)p)[i]) : ((const float*)p)[i];
}
__device__ __forceinline__ int ldi(const void* p, int is64, size_t i) {
    return is64 ? (int)((const long long*)p)[i] : ((const int*)p)[i];
}

// flags[0]=edge_index is int64, flags[1]=node_mask is int64, flags[2]=floats are bf16
// Fused: grid=128 zeroes counts; block 0 / wave 0 additionally runs dtype detection.
__global__ __launch_bounds__(256)
void init_detect_kernel(const void* ei, const void* nm, const void* x,
                        int* __restrict__ flags, int* __restrict__ counts)
{
    const int t = threadIdx.x;
    counts[blockIdx.x * 256 + t] = 0;
    if (blockIdx.x == 0 && t < 64) {
        const long long ev = ((const long long*)ei)[t];
        const unsigned long long okE = __ballot(ev >= 0 && ev < NN);
        const long long mv = ((const long long*)nm)[t];
        const unsigned long long okM = __ballot(mv == 0 || mv == 1);
        const unsigned int w = ((const unsigned int*)x)[t];
        const int e = (w >> 7) & 0xFF;
        const unsigned long long okF = __ballot(e >= 100 && e <= 140);
        if (t == 0) {
            flags[0] = (okE == ~0ULL) ? 1 : 0;
            flags[1] = (okM == ~0ULL) ? 1 : 0;
            flags[2] = (__popcll(okF) >= 40) ? 1 : 0;
        }
    }
}

// ---------------- MFMA GEMM: h[m][n] = sum_k x[m][k] * W[n][k] + b[n] --------------
// Block tile 128(M) x 256(N = full D), BK=64, 512 threads = 8 waves (2m x 4n),
// wave sub-tile 64x64 (4x4 16x16x32 frags). Grid = 256 (1 block/CU, 96 KB LDS);
// x fetched from HBM exactly once. bf16 path: DOUBLE-BUFFERED global_load_lds
// width-16 staging with pre-swizzled global source (linear LDS dest; XOR swizzle
// (row&7)<<4 is an involution so source group cg=(slot&7)^(row&7)); prefetch of
// k-tile kt+1 is issued before compute of kt -> 1 barrier per k-tile, load latency
// hidden under MFMA. fp32 path: register staging hi/lo bf16 split (buffers 0=hi,1=lo).

typedef __attribute__((ext_vector_type(8))) __bf16 bf16x8;
typedef __attribute__((ext_vector_type(4))) float  f32x4;

__device__ __forceinline__ unsigned short f2bf(float f) {
    unsigned u = __float_as_uint(f);
    u = (u + 0x7fffu + ((u >> 16) & 1u)) >> 16;
    return (unsigned short)u;
}
__device__ __forceinline__ float bf2f(unsigned short h) {
    return __uint_as_float(((unsigned)h) << 16);
}
__device__ __forceinline__ void cvt_hilo(float4 f, ushort4* hi, ushort4* lo) {
    const unsigned short h0 = f2bf(f.x), h1 = f2bf(f.y), h2 = f2bf(f.z), h3 = f2bf(f.w);
    *hi = make_ushort4(h0, h1, h2, h3);
    *lo = make_ushort4(f2bf(f.x - bf2f(h0)), f2bf(f.y - bf2f(h1)),
                       f2bf(f.z - bf2f(h2)), f2bf(f.w - bf2f(h3)));
}
// swizzled ds_read_b128 of 8 bf16 at (row, col) in a [*][64]-bf16 LDS tile
__device__ __forceinline__ bf16x8 frag_ld(const unsigned short* base, int row, int col) {
    const int byte = ((row * 64 + col) * 2) ^ ((row & 7) << 4);
    return *(const bf16x8*)((const char*)base + byte);
}
__device__ __forceinline__ void gload16(const void* g, void* l) {
    __builtin_amdgcn_global_load_lds(
        (const __attribute__((address_space(1))) unsigned int*)g,
        (__attribute__((address_space(3))) unsigned int*)l, 16, 0, 0);
}

__global__ __launch_bounds__(512)
void gemm_kernel(const void* __restrict__ x, const void* __restrict__ w,
                 const void* __restrict__ bias, const int* __restrict__ flags,
                 float* __restrict__ h)
{
    __shared__ unsigned short As[2][128 * 64];   // 2 x 16 KB
    __shared__ unsigned short Bs[2][256 * 64];   // 2 x 32 KB  -> 96 KB total

    const int fbf = flags[2];
    const int t = threadIdx.x;
    const int lane = t & 63;
    const int wid = t >> 6;
    const int wr = wid >> 2;        // m-half (64 rows)
    const int wc = wid & 3;         // n-quarter (64 cols)
    const int m0 = (int)blockIdx.x * 128;

    f32x4 acc[4][4];
#pragma unroll
    for (int mi = 0; mi < 4; ++mi)
#pragma unroll
        for (int nj = 0; nj < 4; ++nj)
            acc[mi][nj] = (f32x4){0.f, 0.f, 0.f, 0.f};

    const int lr = lane & 15;
    const int lk8 = (lane >> 4) << 3;

    auto compute_hh = [&](const unsigned short* Ab, const unsigned short* Bb) {
#pragma unroll
        for (int kk = 0; kk < 64; kk += 32) {
            const int lk = kk + lk8;
            bf16x8 aH[4], bH[4];
#pragma unroll
            for (int mi = 0; mi < 4; ++mi)
                aH[mi] = frag_ld(Ab, wr * 64 + mi * 16 + lr, lk);
#pragma unroll
            for (int nj = 0; nj < 4; ++nj)
                bH[nj] = frag_ld(Bb, wc * 64 + nj * 16 + lr, lk);
#pragma unroll
            for (int mi = 0; mi < 4; ++mi)
#pragma unroll
                for (int nj = 0; nj < 4; ++nj)
                    acc[mi][nj] = __builtin_amdgcn_mfma_f32_16x16x32_bf16(
                        aH[mi], bH[nj], acc[mi][nj], 0, 0, 0);
        }
    };

    if (fbf) {
        const unsigned short* xp = (const unsigned short*)x;
        const unsigned short* wp = (const unsigned short*)w;
        auto stage = [&](int kt, int buf) {
            const int k0 = kt * 64;
#pragma unroll
            for (int i = 0; i < 2; ++i) {           // A: 1024 slots, 2/thread
                const int s = i * 512 + t;
                const int row = s >> 3, cg = (s & 7) ^ (row & 7);
                gload16(xp + (size_t)(m0 + row) * 256 + k0 + cg * 8, &As[buf][s * 8]);
            }
#pragma unroll
            for (int i = 0; i < 4; ++i) {           // B: 2048 slots, 4/thread
                const int s = i * 512 + t;
                const int row = s >> 3, cg = (s & 7) ^ (row & 7);
                gload16(wp + (size_t)row * 256 + k0 + cg * 8, &Bs[buf][s * 8]);
            }
        };
        stage(0, 0);
        for (int kt = 0; kt < 4; ++kt) {
            __syncthreads();                    // drains vmcnt -> buf[kt&1] ready;
            if (kt < 3) stage(kt + 1, (kt + 1) & 1);   // also fences buf overwrite
            compute_hh(As[kt & 1], Bs[kt & 1]);
        }
    } else {
        // fp32 fallback: buffers [0]=hi, [1]=lo, single-buffered, 3-term MFMA
        const float* xp = (const float*)x;
        const float* wp = (const float*)w;
        for (int kt = 0; kt < 4; ++kt) {
            const int k0 = kt * 64;
#pragma unroll
            for (int i = 0; i < 2; ++i) {
                const int s = i * 512 + t;
                const int row = s >> 3, cg = (s & 7) ^ (row & 7);
                const float* src = xp + (size_t)(m0 + row) * 256 + k0 + cg * 8;
                const float4 f0 = *(const float4*)src, f1 = *(const float4*)(src + 4);
                ushort4 h0, l0, h1, l1;
                cvt_hilo(f0, &h0, &l0); cvt_hilo(f1, &h1, &l1);
                *(ushort4*)&As[0][s * 8]     = h0; *(ushort4*)&As[0][s * 8 + 4] = h1;
                *(ushort4*)&As[1][s * 8]     = l0; *(ushort4*)&As[1][s * 8 + 4] = l1;
            }
#pragma unroll
            for (int i = 0; i < 4; ++i) {
                const int s = i * 512 + t;
                const int row = s >> 3, cg = (s & 7) ^ (row & 7);
                const float* src = wp + (size_t)row * 256 + k0 + cg * 8;
                const float4 f0 = *(const float4*)src, f1 = *(const float4*)(src + 4);
                ushort4 h0, l0, h1, l1;
                cvt_hilo(f0, &h0, &l0); cvt_hilo(f1, &h1, &l1);
                *(ushort4*)&Bs[0][s * 8]     = h0; *(ushort4*)&Bs[0][s * 8 + 4] = h1;
                *(ushort4*)&Bs[1][s * 8]     = l0; *(ushort4*)&Bs[1][s * 8 + 4] = l1;
            }
            __syncthreads();
            compute_hh(As[0], Bs[0]);
#pragma unroll
            for (int kk = 0; kk < 64; kk += 32) {
                const int lk = kk + lk8;
                bf16x8 aH[4], bH[4], aL[4], bL[4];
#pragma unroll
                for (int mi = 0; mi < 4; ++mi) {
                    aH[mi] = frag_ld(As[0], wr * 64 + mi * 16 + lr, lk);
                    aL[mi] = frag_ld(As[1], wr * 64 + mi * 16 + lr, lk);
                }
#pragma unroll
                for (int nj = 0; nj < 4; ++nj) {
                    bH[nj] = frag_ld(Bs[0], wc * 64 + nj * 16 + lr, lk);
                    bL[nj] = frag_ld(Bs[1], wc * 64 + nj * 16 + lr, lk);
                }
#pragma unroll
                for (int mi = 0; mi < 4; ++mi)
#pragma unroll
                    for (int nj = 0; nj < 4; ++nj) {
                        acc[mi][nj] = __builtin_amdgcn_mfma_f32_16x16x32_bf16(
                            aH[mi], bL[nj], acc[mi][nj], 0, 0, 0);
                        acc[mi][nj] = __builtin_amdgcn_mfma_f32_16x16x32_bf16(
                            aL[mi], bH[nj], acc[mi][nj], 0, 0, 0);
                    }
            }
            __syncthreads();
        }
    }

    // ---- epilogue: +bias, fp32 h. C/D map: col=lane&15, row=(lane>>4)*4+r ----
    const int r4 = (lane >> 4) << 2;
#pragma unroll
    for (int nj = 0; nj < 4; ++nj) {
        const int n = wc * 64 + nj * 16 + lr;
        const float bv = ldf(bias, fbf, n);
#pragma unroll
        for (int mi = 0; mi < 4; ++mi) {
            const int rb = m0 + wr * 64 + mi * 16 + r4;
#pragma unroll
            for (int r = 0; r < 4; ++r)
                h[(size_t)(rb + r) * 256 + n] = acc[mi][nj][r] + bv;
        }
    }
}

// ---------------- CSR build: count -> scan -> fill ---------------------------------
// 2 edges per thread, vector loads of the index pairs.
__global__ __launch_bounds__(256)
void count_kernel(const void* __restrict__ ei, const void* __restrict__ nm,
                  const int* __restrict__ flags, int* __restrict__ counts)
{
    const int e64 = flags[0], m64 = flags[1];
    const int tid = blockIdx.x * 256 + threadIdx.x;   // 0..262143
    const int b = tid >> 15;                          // 32768 threads/batch
    const int k = (tid & 32767) << 1;
    const size_t eb = (size_t)b * 2 * NE;
    int s0, s1, t0, t1;
    if (e64) {
        const longlong2 sv = *(const longlong2*)((const long long*)ei + eb + k);
        const longlong2 tv = *(const longlong2*)((const long long*)ei + eb + NE + k);
        s0 = (int)sv.x; s1 = (int)sv.y; t0 = (int)tv.x; t1 = (int)tv.y;
    } else {
        const int2 sv = *(const int2*)((const int*)ei + eb + k);
        const int2 tv = *(const int2*)((const int*)ei + eb + NE + k);
        s0 = sv.x; s1 = sv.y; t0 = tv.x; t1 = tv.y;
    }
    const size_t mb = (size_t)b * NN;
    if (ldi(nm, m64, mb + s0) && ldi(nm, m64, mb + t0))
        atomicAdd(&counts[b * NN + t0], 1);
    if (ldi(nm, m64, mb + s1) && ldi(nm, m64, mb + t1))
        atomicAdd(&counts[b * NN + t1], 1);
}

// Coalesced transposed scan: thread t owns nodes {i*256+t}. The node->range mapping
// is an arbitrary bijection (bucket order is irrelevant); offsets[] = start, and
// after fill_kernel the cursor array holds start+count = end pointer per node.
__global__ __launch_bounds__(256)
void scan_kernel(int* __restrict__ counts, int* __restrict__ offsets)
{
    __shared__ int sums[256];
    const int t = threadIdx.x;
    int s = 0;
    for (int i = 0; i < 128; ++i) s += counts[i * 256 + t];   // coalesced
    sums[t] = s;
    __syncthreads();
    for (int off = 1; off < 256; off <<= 1) {
        int v = (t >= off) ? sums[t - off] : 0;
        __syncthreads();
        sums[t] += v;
        __syncthreads();
    }
    int run = sums[t] - s;
    for (int i = 0; i < 128; ++i) {                           // coalesced
        const int idx = i * 256 + t;
        const int c = counts[idx];
        offsets[idx] = run;
        counts[idx] = run;      // cursor init for fill_kernel
        run += c;
    }
}

__global__ __launch_bounds__(256)
void fill_kernel(const void* __restrict__ ei, const void* __restrict__ nm,
                 const int* __restrict__ flags,
                 int* __restrict__ cursor, int* __restrict__ bucket)
{
    const int e64 = flags[0], m64 = flags[1];
    const int tid = blockIdx.x * 256 + threadIdx.x;
    const int b = tid >> 15;
    const int k = (tid & 32767) << 1;
    const size_t eb = (size_t)b * 2 * NE;
    int s0, s1, t0, t1;
    if (e64) {
        const longlong2 sv = *(const longlong2*)((const long long*)ei + eb + k);
        const longlong2 tv = *(const longlong2*)((const long long*)ei + eb + NE + k);
        s0 = (int)sv.x; s1 = (int)sv.y; t0 = (int)tv.x; t1 = (int)tv.y;
    } else {
        const int2 sv = *(const int2*)((const int*)ei + eb + k);
        const int2 tv = *(const int2*)((const int*)ei + eb + NE + k);
        s0 = sv.x; s1 = sv.y; t0 = tv.x; t1 = tv.y;
    }
    const size_t mb = (size_t)b * NN;
    if (ldi(nm, m64, mb + s0) && ldi(nm, m64, mb + t0))
        bucket[atomicAdd(&cursor[b * NN + t0], 1)] = s0;
    if (ldi(nm, m64, mb + s1) && ldi(nm, m64, mb + t1))
        bucket[atomicAdd(&cursor[b * NN + t1], 1)] = s1;
}

// ---------------- gather + residual + LayerNorm + ReLU + mask ----------------------
// 4 waves per 256-thread block, one node per wave (no barriers, full occupancy).
// float4 per lane (64 x 4 = 256 dims); LN reduce is pure shfl_xor.
//
// XCD-locality swizzle (T1, batch-structured): each batch's h-slice is 4096 rows x
// 1 KB = 4 MB = exactly one XCD's L2. Dispatch round-robins wgid%8 across the 8
// XCDs (m09), so remap blk = (bid&7)*1024 + (bid>>3): batch b's 1024 blocks all
// land on XCD b, making the ~134 MB of random h-row gathers per-XCD-L2-resident
// instead of thrashing the 32 MB aggregate L2 with all 8 batches. Bijective
// (grid 8192 % 8 == 0); perf-only heuristic, correctness unaffected.
__global__ __launch_bounds__(256)
void node_kernel(const float* __restrict__ h, const int* __restrict__ offsets,
                 const int* __restrict__ ends, const int* __restrict__ bucket,
                 const void* __restrict__ nm, const int* __restrict__ flags,
                 const void* __restrict__ gamma, const void* __restrict__ beta,
                 void* __restrict__ out)
{
    const int blk = ((blockIdx.x & 7) << 10) | (blockIdx.x >> 3);   // XCD swizzle
    const int bt = blk * 4 + (threadIdx.x >> 6);
    const int lane = threadIdx.x & 63;
    const int m64 = flags[1], fbf = flags[2];
    const size_t o4 = (size_t)bt * 64 + lane;     // float4/ushort4 index
    if (!ldi(nm, m64, bt)) {
        if (fbf) ((ushort4*)out)[o4] = make_ushort4(0, 0, 0, 0);
        else     ((float4*)out)[o4]  = make_float4(0.f, 0.f, 0.f, 0.f);
        return;
    }
    const int b = bt >> 12;     // NN = 4096
    const float4* hb = (const float4*)h + ((size_t)b << 12) * 64;
    const float4 self = ((const float4*)h)[o4];
    const int s0 = offsets[bt], s1 = ends[bt];
    float4 a0 = make_float4(0.f, 0.f, 0.f, 0.f), a1 = a0, a2 = a0, a3 = a0;
    int j = s0;
    for (; j + 4 <= s1; j += 4) {
        const float4 v0 = hb[(size_t)bucket[j]     * 64 + lane];
        const float4 v1 = hb[(size_t)bucket[j + 1] * 64 + lane];
        const float4 v2 = hb[(size_t)bucket[j + 2] * 64 + lane];
        const float4 v3 = hb[(size_t)bucket[j + 3] * 64 + lane];
        a0.x += v0.x; a0.y += v0.y; a0.z += v0.z; a0.w += v0.w;
        a1.x += v1.x; a1.y += v1.y; a1.z += v1.z; a1.w += v1.w;
        a2.x += v2.x; a2.y += v2.y; a2.z += v2.z; a2.w += v2.w;
        a3.x += v3.x; a3.y += v3.y; a3.z += v3.z; a3.w += v3.w;
    }
    for (; j < s1; ++j) {
        const float4 v = hb[(size_t)bucket[j] * 64 + lane];
        a0.x += v.x; a0.y += v.y; a0.z += v.z; a0.w += v.w;
    }
    float4 acc;
    acc.x = self.x + ((a0.x + a1.x) + (a2.x + a3.x)) * 0.015625f;  // /sqrt(4096)
    acc.y = self.y + ((a0.y + a1.y) + (a2.y + a3.y)) * 0.015625f;
    acc.z = self.z + ((a0.z + a1.z) + (a2.z + a3.z)) * 0.015625f;
    acc.w = self.w + ((a0.w + a1.w) + (a2.w + a3.w)) * 0.015625f;

    float v1r = (acc.x + acc.y) + (acc.z + acc.w);
    float v2r = (acc.x * acc.x + acc.y * acc.y) + (acc.z * acc.z + acc.w * acc.w);
#pragma unroll
    for (int off = 32; off > 0; off >>= 1) {
        v1r += __shfl_xor(v1r, off, 64);
        v2r += __shfl_xor(v2r, off, 64);
    }
    const float mu  = v1r * (1.f / 256.f);
    const float var = v2r * (1.f / 256.f) - mu * mu;
    const float inv = rsqrtf(var + 1e-5f);
    const int d0 = lane * 4;
    float y0 = (acc.x - mu) * inv * ldf(gamma, fbf, d0)     + ldf(beta, fbf, d0);
    float y1 = (acc.y - mu) * inv * ldf(gamma, fbf, d0 + 1) + ldf(beta, fbf, d0 + 1);
    float y2 = (acc.z - mu) * inv * ldf(gamma, fbf, d0 + 2) + ldf(beta, fbf, d0 + 2);
    float y3 = (acc.w - mu) * inv * ldf(gamma, fbf, d0 + 3) + ldf(beta, fbf, d0 + 3);
    y0 = fmaxf(y0, 0.f); y1 = fmaxf(y1, 0.f); y2 = fmaxf(y2, 0.f); y3 = fmaxf(y3, 0.f);
    if (fbf) ((ushort4*)out)[o4] = make_ushort4(f2bf(y0), f2bf(y1), f2bf(y2), f2bf(y3));
    else     ((float4*)out)[o4]  = make_float4(y0, y1, y2, y3);
}

// host-side sentinel buffer for launch-failure diagnosis (static lifetime: safe
// for async H2D copy; value encodes the first failing stage as absmax ~ 1e4*stage)
static float g_sentinel[256];

extern "C" void kernel_launch(void* const* d_in, const int* in_sizes, int n_in,
                              void* d_out, int out_size, void* d_ws, size_t ws_size,
                              hipStream_t stream)
{
    (void)in_sizes; (void)n_in; (void)out_size;
    const void* x     = d_in[0];
    const void* W     = d_in[1];
    const void* bias  = d_in[2];
    const void* gamma = d_in[3];
    const void* beta  = d_in[4];
    const void* ei    = d_in[5];
    const void* nm    = d_in[6];

    char* ws = (char*)d_ws;
    int* flags   = (int*)ws;                 // @0        12 B
    int* counts  = (int*)(ws + 256);         // @256      131072 B (becomes cursor/end)
    int* offsets = (int*)(ws + 131328);      // @131328   131072 B
    int* bucket  = (int*)(ws + 262656);      // @262656   2097152 B
    float* h     = (float*)(ws + 2359808);   // @2359808  33554432 B (fp32 h)

    int fail = 0;
    hipGetLastError();  // clear any pre-existing error
#define CHK(stage) do { if (!fail && hipGetLastError() != hipSuccess) fail = (stage); } while (0)

    init_detect_kernel<<<TOT_NODES / 256, 256, 0, stream>>>(ei, nm, x, flags, counts); CHK(1);
    gemm_kernel<<<TOT_NODES / 128, 512, 0, stream>>>(x, W, bias, flags, h);            CHK(2);
    count_kernel<<<TOT_EDGES / 512, 256, 0, stream>>>(ei, nm, flags, counts);          CHK(3);
    scan_kernel<<<1, 256, 0, stream>>>(counts, offsets);                               CHK(4);
    fill_kernel<<<TOT_EDGES / 512, 256, 0, stream>>>(ei, nm, flags, counts, bucket);   CHK(5);
    node_kernel<<<TOT_NODES / 4, 256, 0, stream>>>(h, offsets, counts, bucket, nm,
                                                   flags, gamma, beta, d_out);         CHK(6);
#undef CHK

    if (fail) {   // deterministic per-environment -> graph-capture safe
        for (int i = 0; i < 256; ++i) g_sentinel[i] = 10000.f * (float)fail;
        hipMemcpyAsync(d_out, g_sentinel, sizeof(g_sentinel),
                       hipMemcpyHostToDevice, stream);
    }
}

// Round 5
// 155.903 us; speedup vs baseline: 2.1971x; 1.0131x over previous
//
#include <hip/hip_runtime.h>
#include <hip/hip_bf16.h>

// Problem: B=8, N=4096, E=65536, D=256
// h = x@W^T + b; agg = segment_sum(h[src]*m_s*m_t by tgt); h += agg/64;
// out = relu(LN(h)*gamma+beta) * mask
#define NN 4096
#define DIM 256
#define NE 65536
#define TOT_NODES 32768
#define TOT_EDGES 524288

// ---- runtime-dtype accessors (flags decided on device by detect logic) -----------
__device__ __forceinline__ float ldf(const void* p, int isbf, size_t i) {
    return isbf ? __bfloat162float(((const __hip_bfloat16*)p)[i]) : ((const float*)p)[i];
}
__device__ __forceinline__ int ldi(const void* p, int is64, size_t i) {
    return is64 ? (int)((const long long*)p)[i] : ((const int*)p)[i];
}

// flags[0]=edge_index is int64, flags[1]=node_mask is int64, flags[2]=floats are bf16
// Fused: grid=128 zeroes counts; block 0 / wave 0 additionally runs dtype detection.
__global__ __launch_bounds__(256)
void init_detect_kernel(const void* ei, const void* nm, const void* x,
                        int* __restrict__ flags, int* __restrict__ counts)
{
    const int t = threadIdx.x;
    counts[blockIdx.x * 256 + t] = 0;
    if (blockIdx.x == 0 && t < 64) {
        const long long ev = ((const long long*)ei)[t];
        const unsigned long long okE = __ballot(ev >= 0 && ev < NN);
        const long long mv = ((const long long*)nm)[t];
        const unsigned long long okM = __ballot(mv == 0 || mv == 1);
        const unsigned int w = ((const unsigned int*)x)[t];
        const int e = (w >> 7) & 0xFF;
        const unsigned long long okF = __ballot(e >= 100 && e <= 140);
        if (t == 0) {
            flags[0] = (okE == ~0ULL) ? 1 : 0;
            flags[1] = (okM == ~0ULL) ? 1 : 0;
            flags[2] = (__popcll(okF) >= 40) ? 1 : 0;
        }
    }
}

// ---------------- MFMA GEMM: h[m][n] = sum_k x[m][k] * W[n][k] + b[n] --------------
// Block tile 128(M) x 256(N = full D), BK=64, 512 threads = 8 waves (2m x 4n),
// wave sub-tile 64x64 (4x4 16x16x32 frags). Grid = 256 (1 block/CU, 96 KB LDS);
// x fetched from HBM exactly once. bf16 path: DOUBLE-BUFFERED global_load_lds
// width-16 staging with pre-swizzled global source (linear LDS dest; XOR swizzle
// (row&7)<<4 is an involution so source group cg=(slot&7)^(row&7)); prefetch of
// k-tile kt+1 is issued before compute of kt -> 1 barrier per k-tile, load latency
// hidden under MFMA. fp32 path: register staging hi/lo bf16 split (buffers 0=hi,1=lo).
// Epilogue writes BOTH fp32 h (self/LN path: full precision) and a bf16 mirror
// (gather path: the agg term is scaled by 1/64, so bf16 error there is ~3e-3 abs
// pre-LN -> invisible; halves the node_kernel's dominant random-gather traffic and
// shrinks the per-batch slice to 2 MB so it fits per-XCD L2 with headroom).

typedef __attribute__((ext_vector_type(8))) __bf16 bf16x8;
typedef __attribute__((ext_vector_type(4))) float  f32x4;

__device__ __forceinline__ unsigned short f2bf(float f) {
    unsigned u = __float_as_uint(f);
    u = (u + 0x7fffu + ((u >> 16) & 1u)) >> 16;
    return (unsigned short)u;
}
__device__ __forceinline__ float bf2f(unsigned short h) {
    return __uint_as_float(((unsigned)h) << 16);
}
__device__ __forceinline__ void cvt_hilo(float4 f, ushort4* hi, ushort4* lo) {
    const unsigned short h0 = f2bf(f.x), h1 = f2bf(f.y), h2 = f2bf(f.z), h3 = f2bf(f.w);
    *hi = make_ushort4(h0, h1, h2, h3);
    *lo = make_ushort4(f2bf(f.x - bf2f(h0)), f2bf(f.y - bf2f(h1)),
                       f2bf(f.z - bf2f(h2)), f2bf(f.w - bf2f(h3)));
}
// swizzled ds_read_b128 of 8 bf16 at (row, col) in a [*][64]-bf16 LDS tile
__device__ __forceinline__ bf16x8 frag_ld(const unsigned short* base, int row, int col) {
    const int byte = ((row * 64 + col) * 2) ^ ((row & 7) << 4);
    return *(const bf16x8*)((const char*)base + byte);
}
__device__ __forceinline__ void gload16(const void* g, void* l) {
    __builtin_amdgcn_global_load_lds(
        (const __attribute__((address_space(1))) unsigned int*)g,
        (__attribute__((address_space(3))) unsigned int*)l, 16, 0, 0);
}

__global__ __launch_bounds__(512)
void gemm_kernel(const void* __restrict__ x, const void* __restrict__ w,
                 const void* __restrict__ bias, const int* __restrict__ flags,
                 float* __restrict__ h, unsigned short* __restrict__ hb16)
{
    __shared__ unsigned short As[2][128 * 64];   // 2 x 16 KB
    __shared__ unsigned short Bs[2][256 * 64];   // 2 x 32 KB  -> 96 KB total

    const int fbf = flags[2];
    const int t = threadIdx.x;
    const int lane = t & 63;
    const int wid = t >> 6;
    const int wr = wid >> 2;        // m-half (64 rows)
    const int wc = wid & 3;         // n-quarter (64 cols)
    const int m0 = (int)blockIdx.x * 128;

    f32x4 acc[4][4];
#pragma unroll
    for (int mi = 0; mi < 4; ++mi)
#pragma unroll
        for (int nj = 0; nj < 4; ++nj)
            acc[mi][nj] = (f32x4){0.f, 0.f, 0.f, 0.f};

    const int lr = lane & 15;
    const int lk8 = (lane >> 4) << 3;

    auto compute_hh = [&](const unsigned short* Ab, const unsigned short* Bb) {
#pragma unroll
        for (int kk = 0; kk < 64; kk += 32) {
            const int lk = kk + lk8;
            bf16x8 aH[4], bH[4];
#pragma unroll
            for (int mi = 0; mi < 4; ++mi)
                aH[mi] = frag_ld(Ab, wr * 64 + mi * 16 + lr, lk);
#pragma unroll
            for (int nj = 0; nj < 4; ++nj)
                bH[nj] = frag_ld(Bb, wc * 64 + nj * 16 + lr, lk);
#pragma unroll
            for (int mi = 0; mi < 4; ++mi)
#pragma unroll
                for (int nj = 0; nj < 4; ++nj)
                    acc[mi][nj] = __builtin_amdgcn_mfma_f32_16x16x32_bf16(
                        aH[mi], bH[nj], acc[mi][nj], 0, 0, 0);
        }
    };

    if (fbf) {
        const unsigned short* xp = (const unsigned short*)x;
        const unsigned short* wp = (const unsigned short*)w;
        auto stage = [&](int kt, int buf) {
            const int k0 = kt * 64;
#pragma unroll
            for (int i = 0; i < 2; ++i) {           // A: 1024 slots, 2/thread
                const int s = i * 512 + t;
                const int row = s >> 3, cg = (s & 7) ^ (row & 7);
                gload16(xp + (size_t)(m0 + row) * 256 + k0 + cg * 8, &As[buf][s * 8]);
            }
#pragma unroll
            for (int i = 0; i < 4; ++i) {           // B: 2048 slots, 4/thread
                const int s = i * 512 + t;
                const int row = s >> 3, cg = (s & 7) ^ (row & 7);
                gload16(wp + (size_t)row * 256 + k0 + cg * 8, &Bs[buf][s * 8]);
            }
        };
        stage(0, 0);
        for (int kt = 0; kt < 4; ++kt) {
            __syncthreads();                    // drains vmcnt -> buf[kt&1] ready;
            if (kt < 3) stage(kt + 1, (kt + 1) & 1);   // also fences buf overwrite
            compute_hh(As[kt & 1], Bs[kt & 1]);
        }
    } else {
        // fp32 fallback: buffers [0]=hi, [1]=lo, single-buffered, 3-term MFMA
        const float* xp = (const float*)x;
        const float* wp = (const float*)w;
        for (int kt = 0; kt < 4; ++kt) {
            const int k0 = kt * 64;
#pragma unroll
            for (int i = 0; i < 2; ++i) {
                const int s = i * 512 + t;
                const int row = s >> 3, cg = (s & 7) ^ (row & 7);
                const float* src = xp + (size_t)(m0 + row) * 256 + k0 + cg * 8;
                const float4 f0 = *(const float4*)src, f1 = *(const float4*)(src + 4);
                ushort4 h0, l0, h1, l1;
                cvt_hilo(f0, &h0, &l0); cvt_hilo(f1, &h1, &l1);
                *(ushort4*)&As[0][s * 8]     = h0; *(ushort4*)&As[0][s * 8 + 4] = h1;
                *(ushort4*)&As[1][s * 8]     = l0; *(ushort4*)&As[1][s * 8 + 4] = l1;
            }
#pragma unroll
            for (int i = 0; i < 4; ++i) {
                const int s = i * 512 + t;
                const int row = s >> 3, cg = (s & 7) ^ (row & 7);
                const float* src = wp + (size_t)row * 256 + k0 + cg * 8;
                const float4 f0 = *(const float4*)src, f1 = *(const float4*)(src + 4);
                ushort4 h0, l0, h1, l1;
                cvt_hilo(f0, &h0, &l0); cvt_hilo(f1, &h1, &l1);
                *(ushort4*)&Bs[0][s * 8]     = h0; *(ushort4*)&Bs[0][s * 8 + 4] = h1;
                *(ushort4*)&Bs[1][s * 8]     = l0; *(ushort4*)&Bs[1][s * 8 + 4] = l1;
            }
            __syncthreads();
            compute_hh(As[0], Bs[0]);
#pragma unroll
            for (int kk = 0; kk < 64; kk += 32) {
                const int lk = kk + lk8;
                bf16x8 aH[4], bH[4], aL[4], bL[4];
#pragma unroll
                for (int mi = 0; mi < 4; ++mi) {
                    aH[mi] = frag_ld(As[0], wr * 64 + mi * 16 + lr, lk);
                    aL[mi] = frag_ld(As[1], wr * 64 + mi * 16 + lr, lk);
                }
#pragma unroll
                for (int nj = 0; nj < 4; ++nj) {
                    bH[nj] = frag_ld(Bs[0], wc * 64 + nj * 16 + lr, lk);
                    bL[nj] = frag_ld(Bs[1], wc * 64 + nj * 16 + lr, lk);
                }
#pragma unroll
                for (int mi = 0; mi < 4; ++mi)
#pragma unroll
                    for (int nj = 0; nj < 4; ++nj) {
                        acc[mi][nj] = __builtin_amdgcn_mfma_f32_16x16x32_bf16(
                            aH[mi], bL[nj], acc[mi][nj], 0, 0, 0);
                        acc[mi][nj] = __builtin_amdgcn_mfma_f32_16x16x32_bf16(
                            aL[mi], bH[nj], acc[mi][nj], 0, 0, 0);
                    }
            }
            __syncthreads();
        }
    }

    // ---- epilogue: +bias, write fp32 h AND bf16 mirror ----
    // C/D map: col=lane&15, row=(lane>>4)*4+r
    const int r4 = (lane >> 4) << 2;
#pragma unroll
    for (int nj = 0; nj < 4; ++nj) {
        const int n = wc * 64 + nj * 16 + lr;
        const float bv = ldf(bias, fbf, n);
#pragma unroll
        for (int mi = 0; mi < 4; ++mi) {
            const int rb = m0 + wr * 64 + mi * 16 + r4;
#pragma unroll
            for (int r = 0; r < 4; ++r) {
                const float v = acc[mi][nj][r] + bv;
                const size_t idx = (size_t)(rb + r) * 256 + n;
                h[idx] = v;
                hb16[idx] = f2bf(v);
            }
        }
    }
}

// ---------------- CSR build: count -> scan -> fill ---------------------------------
// 2 edges per thread, vector loads of the index pairs.
__global__ __launch_bounds__(256)
void count_kernel(const void* __restrict__ ei, const void* __restrict__ nm,
                  const int* __restrict__ flags, int* __restrict__ counts)
{
    const int e64 = flags[0], m64 = flags[1];
    const int tid = blockIdx.x * 256 + threadIdx.x;   // 0..262143
    const int b = tid >> 15;                          // 32768 threads/batch
    const int k = (tid & 32767) << 1;
    const size_t eb = (size_t)b * 2 * NE;
    int s0, s1, t0, t1;
    if (e64) {
        const longlong2 sv = *(const longlong2*)((const long long*)ei + eb + k);
        const longlong2 tv = *(const longlong2*)((const long long*)ei + eb + NE + k);
        s0 = (int)sv.x; s1 = (int)sv.y; t0 = (int)tv.x; t1 = (int)tv.y;
    } else {
        const int2 sv = *(const int2*)((const int*)ei + eb + k);
        const int2 tv = *(const int2*)((const int*)ei + eb + NE + k);
        s0 = sv.x; s1 = sv.y; t0 = tv.x; t1 = tv.y;
    }
    const size_t mb = (size_t)b * NN;
    if (ldi(nm, m64, mb + s0) && ldi(nm, m64, mb + t0))
        atomicAdd(&counts[b * NN + t0], 1);
    if (ldi(nm, m64, mb + s1) && ldi(nm, m64, mb + t1))
        atomicAdd(&counts[b * NN + t1], 1);
}

// Parallel per-batch scan: 8 blocks (one per batch), bucket space partitioned at
// b*NE (per-batch active edges <= NE by construction, so regions never overlap).
// Thread t owns nodes {i*256+t} within its batch (coalesced); 16 rounds instead of
// the previous single-block 128. offsets[] = global start; after fill_kernel the
// cursor array holds start+count = end pointer per node.
__global__ __launch_bounds__(256)
void scan_kernel(int* __restrict__ counts, int* __restrict__ offsets)
{
    __shared__ int sums[256];
    const int b = blockIdx.x;
    const int t = threadIdx.x;
    const int base = b * NN;
    int s = 0;
#pragma unroll
    for (int i = 0; i < 16; ++i) s += counts[base + i * 256 + t];   // coalesced
    sums[t] = s;
    __syncthreads();
    for (int off = 1; off < 256; off <<= 1) {
        int v = (t >= off) ? sums[t - off] : 0;
        __syncthreads();
        sums[t] += v;
        __syncthreads();
    }
    int run = b * NE + sums[t] - s;     // batch region base + exclusive prefix
#pragma unroll
    for (int i = 0; i < 16; ++i) {                                  // coalesced
        const int idx = base + i * 256 + t;
        const int c = counts[idx];
        offsets[idx] = run;
        counts[idx] = run;      // cursor init for fill_kernel
        run += c;
    }
}

__global__ __launch_bounds__(256)
void fill_kernel(const void* __restrict__ ei, const void* __restrict__ nm,
                 const int* __restrict__ flags,
                 int* __restrict__ cursor, int* __restrict__ bucket)
{
    const int e64 = flags[0], m64 = flags[1];
    const int tid = blockIdx.x * 256 + threadIdx.x;
    const int b = tid >> 15;
    const int k = (tid & 32767) << 1;
    const size_t eb = (size_t)b * 2 * NE;
    int s0, s1, t0, t1;
    if (e64) {
        const longlong2 sv = *(const longlong2*)((const long long*)ei + eb + k);
        const longlong2 tv = *(const longlong2*)((const long long*)ei + eb + NE + k);
        s0 = (int)sv.x; s1 = (int)sv.y; t0 = (int)tv.x; t1 = (int)tv.y;
    } else {
        const int2 sv = *(const int2*)((const int*)ei + eb + k);
        const int2 tv = *(const int2*)((const int*)ei + eb + NE + k);
        s0 = sv.x; s1 = sv.y; t0 = tv.x; t1 = tv.y;
    }
    const size_t mb = (size_t)b * NN;
    if (ldi(nm, m64, mb + s0) && ldi(nm, m64, mb + t0))
        bucket[atomicAdd(&cursor[b * NN + t0], 1)] = s0;
    if (ldi(nm, m64, mb + s1) && ldi(nm, m64, mb + t1))
        bucket[atomicAdd(&cursor[b * NN + t1], 1)] = s1;
}

// ---------------- gather + residual + LayerNorm + ReLU + mask ----------------------
// 4 waves per 256-thread block, one node per wave (no barriers, full occupancy).
// Neighbor rows gathered from the bf16 mirror (512 B/row, ushort4/lane): halves the
// dominant random traffic; the agg term is scaled by 1/64 so bf16 error is
// negligible. Self row + LN stay fp32.
//
// XCD-locality swizzle (T1, batch-structured): each batch's bf16 slice is now
// 4096 x 512 B = 2 MB, fitting one XCD's 4 MB L2 with headroom. Dispatch
// round-robins wgid%8 across the 8 XCDs (m09); remap blk=(bid&7)*1024+(bid>>3)
// puts batch b's 1024 blocks all on XCD b -> gathers become per-XCD-L2-resident.
// Bijective (8192%8==0); perf-only heuristic, correctness unaffected.
__global__ __launch_bounds__(256)
void node_kernel(const float* __restrict__ h, const unsigned short* __restrict__ hb16,
                 const int* __restrict__ offsets,
                 const int* __restrict__ ends, const int* __restrict__ bucket,
                 const void* __restrict__ nm, const int* __restrict__ flags,
                 const void* __restrict__ gamma, const void* __restrict__ beta,
                 void* __restrict__ out)
{
    const int blk = ((blockIdx.x & 7) << 10) | (blockIdx.x >> 3);   // XCD swizzle
    const int bt = blk * 4 + (threadIdx.x >> 6);
    const int lane = threadIdx.x & 63;
    const int m64 = flags[1], fbf = flags[2];
    const size_t o4 = (size_t)bt * 64 + lane;     // float4/ushort4 index
    if (!ldi(nm, m64, bt)) {
        if (fbf) ((ushort4*)out)[o4] = make_ushort4(0, 0, 0, 0);
        else     ((float4*)out)[o4]  = make_float4(0.f, 0.f, 0.f, 0.f);
        return;
    }
    const int b = bt >> 12;     // NN = 4096
    const ushort4* hg = (const ushort4*)hb16 + ((size_t)b << 12) * 64;
    const float4 self = ((const float4*)h)[o4];
    const int s0 = offsets[bt], s1 = ends[bt];
    float4 a0 = make_float4(0.f, 0.f, 0.f, 0.f), a1 = a0, a2 = a0, a3 = a0;
    int j = s0;
    for (; j + 4 <= s1; j += 4) {
        const ushort4 u0 = hg[(size_t)bucket[j]     * 64 + lane];
        const ushort4 u1 = hg[(size_t)bucket[j + 1] * 64 + lane];
        const ushort4 u2 = hg[(size_t)bucket[j + 2] * 64 + lane];
        const ushort4 u3 = hg[(size_t)bucket[j + 3] * 64 + lane];
        a0.x += bf2f(u0.x); a0.y += bf2f(u0.y); a0.z += bf2f(u0.z); a0.w += bf2f(u0.w);
        a1.x += bf2f(u1.x); a1.y += bf2f(u1.y); a1.z += bf2f(u1.z); a1.w += bf2f(u1.w);
        a2.x += bf2f(u2.x); a2.y += bf2f(u2.y); a2.z += bf2f(u2.z); a2.w += bf2f(u2.w);
        a3.x += bf2f(u3.x); a3.y += bf2f(u3.y); a3.z += bf2f(u3.z); a3.w += bf2f(u3.w);
    }
    for (; j < s1; ++j) {
        const ushort4 u = hg[(size_t)bucket[j] * 64 + lane];
        a0.x += bf2f(u.x); a0.y += bf2f(u.y); a0.z += bf2f(u.z); a0.w += bf2f(u.w);
    }
    float4 acc;
    acc.x = self.x + ((a0.x + a1.x) + (a2.x + a3.x)) * 0.015625f;  // /sqrt(4096)
    acc.y = self.y + ((a0.y + a1.y) + (a2.y + a3.y)) * 0.015625f;
    acc.z = self.z + ((a0.z + a1.z) + (a2.z + a3.z)) * 0.015625f;
    acc.w = self.w + ((a0.w + a1.w) + (a2.w + a3.w)) * 0.015625f;

    float v1r = (acc.x + acc.y) + (acc.z + acc.w);
    float v2r = (acc.x * acc.x + acc.y * acc.y) + (acc.z * acc.z + acc.w * acc.w);
#pragma unroll
    for (int off = 32; off > 0; off >>= 1) {
        v1r += __shfl_xor(v1r, off, 64);
        v2r += __shfl_xor(v2r, off, 64);
    }
    const float mu  = v1r * (1.f / 256.f);
    const float var = v2r * (1.f / 256.f) - mu * mu;
    const float inv = rsqrtf(var + 1e-5f);
    const int d0 = lane * 4;
    float y0 = (acc.x - mu) * inv * ldf(gamma, fbf, d0)     + ldf(beta, fbf, d0);
    float y1 = (acc.y - mu) * inv * ldf(gamma, fbf, d0 + 1) + ldf(beta, fbf, d0 + 1);
    float y2 = (acc.z - mu) * inv * ldf(gamma, fbf, d0 + 2) + ldf(beta, fbf, d0 + 2);
    float y3 = (acc.w - mu) * inv * ldf(gamma, fbf, d0 + 3) + ldf(beta, fbf, d0 + 3);
    y0 = fmaxf(y0, 0.f); y1 = fmaxf(y1, 0.f); y2 = fmaxf(y2, 0.f); y3 = fmaxf(y3, 0.f);
    if (fbf) ((ushort4*)out)[o4] = make_ushort4(f2bf(y0), f2bf(y1), f2bf(y2), f2bf(y3));
    else     ((float4*)out)[o4]  = make_float4(y0, y1, y2, y3);
}

// host-side sentinel buffer for launch-failure diagnosis (static lifetime: safe
// for async H2D copy; value encodes the first failing stage as absmax ~ 1e4*stage)
static float g_sentinel[256];

extern "C" void kernel_launch(void* const* d_in, const int* in_sizes, int n_in,
                              void* d_out, int out_size, void* d_ws, size_t ws_size,
                              hipStream_t stream)
{
    (void)in_sizes; (void)n_in; (void)out_size;
    const void* x     = d_in[0];
    const void* W     = d_in[1];
    const void* bias  = d_in[2];
    const void* gamma = d_in[3];
    const void* beta  = d_in[4];
    const void* ei    = d_in[5];
    const void* nm    = d_in[6];

    char* ws = (char*)d_ws;
    int* flags   = (int*)ws;                   // @0        12 B
    int* counts  = (int*)(ws + 256);           // @256      131072 B (becomes cursor/end)
    int* offsets = (int*)(ws + 131328);        // @131328   131072 B
    int* bucket  = (int*)(ws + 262656);        // @262656   2097152 B
    float* h     = (float*)(ws + 2359808);     // @2359808  33554432 B (fp32 h)
    unsigned short* hb16 = (unsigned short*)(ws + 35914240);  // @35914240 16777216 B

    int fail = 0;
    hipGetLastError();  // clear any pre-existing error
#define CHK(stage) do { if (!fail && hipGetLastError() != hipSuccess) fail = (stage); } while (0)

    init_detect_kernel<<<TOT_NODES / 256, 256, 0, stream>>>(ei, nm, x, flags, counts); CHK(1);
    gemm_kernel<<<TOT_NODES / 128, 512, 0, stream>>>(x, W, bias, flags, h, hb16);      CHK(2);
    count_kernel<<<TOT_EDGES / 512, 256, 0, stream>>>(ei, nm, flags, counts);          CHK(3);
    scan_kernel<<<8, 256, 0, stream>>>(counts, offsets);                               CHK(4);
    fill_kernel<<<TOT_EDGES / 512, 256, 0, stream>>>(ei, nm, flags, counts, bucket);   CHK(5);
    node_kernel<<<TOT_NODES / 4, 256, 0, stream>>>(h, hb16, offsets, counts, bucket,
                                                   nm, flags, gamma, beta, d_out);     CHK(6);
#undef CHK

    if (fail) {   // deterministic per-environment -> graph-capture safe
        for (int i = 0; i < 256; ++i) g_sentinel[i] = 10000.f * (float)fail;
        hipMemcpyAsync(d_out, g_sentinel, sizeof(g_sentinel),
                       hipMemcpyHostToDevice, stream);
    }
}